// Round 4
// baseline (622.098 us; speedup 1.0000x reference)
//
#include <hip/hip_runtime.h>
#include <math.h>

#define NN 50000
#define NE 800000
#define FIN 128
#define HEADS 4
#define HID 32
#define D1 128
#define NCLS 16
#define NEG 0.2f
#define NINF (-3.402823466e38f)
#define CAP 64
#define SB 256
#define NSB ((NN + SB - 1) / SB)  // 196
#define PGRID 2048               // persistent grid: 8 blocks/CU x 256 CU

typedef unsigned long long ull;
typedef __attribute__((ext_vector_type(2))) unsigned long long ull2;
typedef __attribute__((ext_vector_type(8))) short bf16x8;
typedef __attribute__((ext_vector_type(4))) float f32x4;

// float -> bf16 bits, round-to-nearest-even
__device__ __forceinline__ short f2bf(float v) {
  unsigned u = __float_as_uint(v);
  unsigned r = (u + 0x7fffu + ((u >> 16) & 1u)) >> 16;
  return (short)r;
}

// ---------------- CSR build ----------------
__global__ void k_count(const int* __restrict__ dst, int* __restrict__ counts) {
  int j = blockIdx.x * 256 + threadIdx.x;
  if (j < NE) atomicAdd(&counts[dst[j]], 1);
}

__global__ void k_scanA(const int* __restrict__ counts, int* __restrict__ bsum) {
  int b = blockIdx.x, t = threadIdx.x;
  int idx = b * SB + t;
  int v = idx < NN ? counts[idx] : 0;
  __shared__ int ws[4];
#pragma unroll
  for (int o = 1; o <= 32; o <<= 1) v += __shfl_xor(v, o, 64);
  if ((t & 63) == 0) ws[t >> 6] = v;
  __syncthreads();
  if (t == 0) bsum[b] = ws[0] + ws[1] + ws[2] + ws[3];
}

__global__ void k_scanB(const int* __restrict__ bsum, int* __restrict__ boff) {
  int t = threadIdx.x;
  int v = t < NSB ? bsum[t] : 0;
  __shared__ int tmp[256];
  tmp[t] = v;
  __syncthreads();
  for (int o = 1; o < 256; o <<= 1) {
    int u = t >= o ? tmp[t - o] : 0;
    __syncthreads();
    tmp[t] += u;
    __syncthreads();
  }
  if (t < NSB) boff[t] = tmp[t] - v;  // exclusive
}

__global__ void k_scanC(const int* __restrict__ counts, const int* __restrict__ boff,
                        int* __restrict__ starts, int* __restrict__ cursor) {
  int b = blockIdx.x, t = threadIdx.x;
  int idx = b * SB + t;
  int v = idx < NN ? counts[idx] : 0;
  __shared__ int tmp[256];
  tmp[t] = v;
  __syncthreads();
  for (int o = 1; o < 256; o <<= 1) {
    int u = t >= o ? tmp[t - o] : 0;
    __syncthreads();
    tmp[t] += u;
    __syncthreads();
  }
  int ex = tmp[t] - v + boff[b];
  if (idx < NN) { starts[idx] = ex; cursor[idx] = ex; }
}

// packed scatter: one 8B write instead of two random 4B writes
__global__ void k_scatter(const int* __restrict__ src, const int* __restrict__ dst,
                          int* __restrict__ cursor, int2* __restrict__ epair) {
  int j = blockIdx.x * 256 + threadIdx.x;
  if (j < NE) {
    int s = src[j];
    int p = atomicAdd(&cursor[dst[j]], 1);
    epair[p] = make_int2(s, j);  // .x = src node, .y = edge id
  }
}

// ---------------- fp32 tiled GEMM, dual-B (cols < N1 from B1, else B2) ----------------
// k-accumulation order is global-k ascending -> bit-identical across tilings.
template <int BM, int BN, int BK, int TM, int TN, int ACT>
__global__ __launch_bounds__(256) void k_gemm2(
    const float* __restrict__ A, const float* __restrict__ B1,
    const float* __restrict__ B2, int N1, int s1, int s2,
    const float* __restrict__ bias, float* __restrict__ C, int M, int N, int K) {
  constexpr int NT = (BM / TM) * (BN / TN);
  static_assert(NT == 256, "block must be 256 threads");
  static_assert(TM % 4 == 0 && TN % 4 == 0, "float4 fragments");
  __shared__ float As[BK][BM + 4];
  __shared__ float Bs[BK][BN];
  int tid = threadIdx.x;
  int bm = blockIdx.y * BM, bn = blockIdx.x * BN;
  constexpr int TX = BN / TN;
  int tn = (tid % TX) * TN;
  int tm = (tid / TX) * TM;
  float acc[TM][TN];
#pragma unroll
  for (int i = 0; i < TM; i++)
#pragma unroll
    for (int j = 0; j < TN; j++) acc[i][j] = 0.f;

  for (int k0 = 0; k0 < K; k0 += BK) {
    constexpr int AV = BM * BK / 4;
    for (int i = tid; i < AV; i += NT) {
      int r = i / (BK / 4);
      int c4 = (i % (BK / 4)) * 4;
      float4 v = make_float4(0.f, 0.f, 0.f, 0.f);
      int gr = bm + r;
      if (gr < M) v = *(const float4*)(A + (size_t)gr * K + k0 + c4);
      As[c4 + 0][r] = v.x; As[c4 + 1][r] = v.y; As[c4 + 2][r] = v.z; As[c4 + 3][r] = v.w;
    }
    constexpr int BV = BK * BN / 4;
    for (int i = tid; i < BV; i += NT) {
      int r = i / (BN / 4), c4 = (i % (BN / 4)) * 4;
      int gc = bn + c4, gk = k0 + r;
      float4 v = (gc < N1) ? *(const float4*)(B1 + (size_t)gk * s1 + gc)
                           : *(const float4*)(B2 + (size_t)gk * s2 + (gc - N1));
      Bs[r][c4 + 0] = v.x; Bs[r][c4 + 1] = v.y; Bs[r][c4 + 2] = v.z; Bs[r][c4 + 3] = v.w;
    }
    __syncthreads();
#pragma unroll
    for (int kk = 0; kk < BK; kk++) {
      float ra[TM], rb[TN];
#pragma unroll
      for (int i = 0; i < TM; i += 4)
        *(float4*)&ra[i] = *(const float4*)&As[kk][tm + i];
#pragma unroll
      for (int j = 0; j < TN; j += 4)
        *(float4*)&rb[j] = *(const float4*)&Bs[kk][tn + j];
#pragma unroll
      for (int i = 0; i < TM; i++)
#pragma unroll
        for (int j = 0; j < TN; j++) acc[i][j] += ra[i] * rb[j];
    }
    __syncthreads();
  }
#pragma unroll
  for (int i = 0; i < TM; i++) {
    int gr = bm + tm + i;
    if (gr >= M) continue;
#pragma unroll
    for (int j = 0; j < TN; j += 4) {
      float4 v;
      v.x = acc[i][j + 0]; v.y = acc[i][j + 1]; v.z = acc[i][j + 2]; v.w = acc[i][j + 3];
      if (bias) {
        v.x += bias[bn + tn + j + 0]; v.y += bias[bn + tn + j + 1];
        v.z += bias[bn + tn + j + 2]; v.w += bias[bn + tn + j + 3];
      }
      if (ACT == 1) {
        v.x = v.x > 0.f ? v.x : (__expf(v.x) - 1.f);
        v.y = v.y > 0.f ? v.y : (__expf(v.y) - 1.f);
        v.z = v.z > 0.f ? v.z : (__expf(v.z) - 1.f);
        v.w = v.w > 0.f ? v.w : (__expf(v.w) - 1.f);
      }
      *(float4*)(C + (size_t)gr * N + bn + tn + j) = v;
    }
  }
}

// ---------------- bf16 weight transpose ----------------
__global__ void k_cvtw(const float* __restrict__ l1w, const float* __restrict__ l2w,
                       short* __restrict__ w1t, short* __restrict__ w2t) {
  int t = blockIdx.x * 256 + threadIdx.x;
  if (t < 128 * 128) {
    int n = t >> 7, k = t & 127;
    w1t[t] = f2bf(l1w[k * 128 + n]);
  }
  if (t < 16 * 128) {
    int n = t >> 7, k = t & 127;
    w2t[t] = f2bf(l2w[k * 16 + n]);
  }
}

// ---------------- MFMA MLP layer 1: C = bf16(elu(A@B + bias)) ----------------
__global__ __launch_bounds__(256) void k_mlp1(
    const short* __restrict__ A, const short* __restrict__ BT,
    const float* __restrict__ bias, short* __restrict__ C) {
  int wv = threadIdx.x >> 6, lane = threadIdx.x & 63;
  int m0 = (blockIdx.x * 4 + wv) * 16;
  int quad = lane >> 4;
  int mr = m0 + (lane & 15);
  bool mok = mr < NN;
  bf16x8 afr[4];
#pragma unroll
  for (int kt = 0; kt < 4; kt++) {
    bf16x8 z = {0, 0, 0, 0, 0, 0, 0, 0};
    afr[kt] = mok ? *(const bf16x8*)(A + (size_t)mr * 128 + kt * 32 + quad * 8) : z;
  }
#pragma unroll
  for (int nt = 0; nt < 8; nt++) {
    f32x4 acc = {0.f, 0.f, 0.f, 0.f};
    int nc = nt * 16 + (lane & 15);
#pragma unroll
    for (int kt = 0; kt < 4; kt++) {
      bf16x8 bfr = *(const bf16x8*)(BT + (size_t)nc * 128 + kt * 32 + quad * 8);
      acc = __builtin_amdgcn_mfma_f32_16x16x32_bf16(afr[kt], bfr, acc, 0, 0, 0);
    }
    float bval = bias[nc];
#pragma unroll
    for (int r = 0; r < 4; r++) {
      int row = m0 + quad * 4 + r;  // C/D: col=lane&15, row=quad*4+reg
      if (row < NN) {
        float v = acc[r] + bval;
        v = v > 0.f ? v : (__expf(v) - 1.f);
        C[(size_t)row * 128 + nc] = f2bf(v);
      }
    }
  }
}

// ---------------- MFMA MLP layer 2 + fused log_softmax ----------------
__global__ __launch_bounds__(256) void k_mlp2(
    const short* __restrict__ A, const short* __restrict__ BT,
    const float* __restrict__ bias, float* __restrict__ out) {
  int wv = threadIdx.x >> 6, lane = threadIdx.x & 63;
  int m0 = (blockIdx.x * 4 + wv) * 16;
  int quad = lane >> 4, col = lane & 15;
  int mr = m0 + col;
  bool mok = mr < NN;
  f32x4 acc = {0.f, 0.f, 0.f, 0.f};
#pragma unroll
  for (int kt = 0; kt < 4; kt++) {
    bf16x8 z = {0, 0, 0, 0, 0, 0, 0, 0};
    bf16x8 afr = mok ? *(const bf16x8*)(A + (size_t)mr * 128 + kt * 32 + quad * 8) : z;
    bf16x8 bfr = *(const bf16x8*)(BT + (size_t)col * 128 + kt * 32 + quad * 8);
    acc = __builtin_amdgcn_mfma_f32_16x16x32_bf16(afr, bfr, acc, 0, 0, 0);
  }
  float bval = bias[col];
#pragma unroll
  for (int r = 0; r < 4; r++) {
    float v = acc[r] + bval;
    float m = v;
#pragma unroll
    for (int o = 1; o <= 8; o <<= 1) m = fmaxf(m, __shfl_xor(m, o, 64));
    float e = __expf(v - m), s = e;
#pragma unroll
    for (int o = 1; o <= 8; o <<= 1) s += __shfl_xor(s, o, 64);
    int row = m0 + quad * 4 + r;
    if (row < NN) out[(size_t)row * NCLS + col] = v - (m + logf(s));
  }
}

// order-preserving float->uint map (lex (score desc,id asc) == u64 desc compare)
__device__ __forceinline__ unsigned fkey(float f) {
  unsigned u = __float_as_uint(f);
  return u ^ (((int)u >> 31) | 0x80000000u);
}

// ===== k_fused1 helpers (tail rows >=16) =====
#define SC1_MACRED()                                                         \
  _Pragma("unroll") for (int j_ = 0; j_ < 4; j_++) {                         \
    float a_, p_ = 0.f;                                                      \
    a_ = xv_[j_].x + xrv.x; p_ += fmaxf(a_, NEG * a_) * attv.x;              \
    a_ = xv_[j_].y + xrv.y; p_ += fmaxf(a_, NEG * a_) * attv.y;              \
    a_ = xv_[j_].z + xrv.z; p_ += fmaxf(a_, NEG * a_) * attv.z;              \
    a_ = xv_[j_].w + xrv.w; p_ += fmaxf(a_, NEG * a_) * attv.w;              \
    pp_[j_] = p_;                                                            \
  }                                                                          \
  _Pragma("unroll") for (int o_ = 1; o_ <= 4; o_ <<= 1)                      \
    _Pragma("unroll") for (int j_ = 0; j_ < 4; j_++)                         \
      pp_[j_] += __shfl_xor(pp_[j_], o_, 64);

#define SC1_FULL(Q)                                                          \
  do {                                                                       \
    int s_[4]; float4 xv_[4]; float pp_[4];                                  \
    _Pragma("unroll") for (int j_ = 0; j_ < 4; j_++)                         \
      s_[j_] = __shfl(srcreg, (Q) + 2 * j_ + h2);                            \
    _Pragma("unroll") for (int j_ = 0; j_ < 4; j_++)                         \
      xv_[j_] = *(const float4*)(xlr + (size_t)s_[j_] * 256 + 4 * li);       \
    SC1_MACRED()                                                             \
    if ((li & 7) == 0) {                                                     \
      _Pragma("unroll") for (int j_ = 0; j_ < 4; j_++)                       \
        sc[w][(Q) + 2 * j_ + h2][headq] = pp_[j_];                           \
    }                                                                        \
  } while (0)

#define SC1_TAIL(Q)                                                          \
  do {                                                                       \
    int s_[4]; float4 xv_[4]; float pp_[4]; bool vv_[4];                     \
    _Pragma("unroll") for (int j_ = 0; j_ < 4; j_++) {                       \
      int r_ = (Q) + 2 * j_ + h2;                                            \
      s_[j_] = __shfl(srcreg, r_);                                           \
      vv_[j_] = r_ < deg;                                                    \
    }                                                                        \
    _Pragma("unroll") for (int j_ = 0; j_ < 4; j_++) {                       \
      xv_[j_] = make_float4(0.f, 0.f, 0.f, 0.f);                             \
      if (vv_[j_])                                                           \
        xv_[j_] = *(const float4*)(xlr + (size_t)s_[j_] * 256 + 4 * li);     \
    }                                                                        \
    SC1_MACRED()                                                             \
    if ((li & 7) == 0) {                                                     \
      _Pragma("unroll") for (int j_ = 0; j_ < 4; j_++)                       \
        if (vv_[j_]) sc[w][(Q) + 2 * j_ + h2][headq] = pp_[j_];              \
    }                                                                        \
  } while (0)

#define AGG1_FMA(WV, XV)                                                     \
  do {                                                                       \
    float pw_ = fmaxf((WV), 0.f), nw_ = pw_ - (WV);                          \
    ao.x += pw_ * (XV).x; ao.y += pw_ * (XV).y;                              \
    ao.z += pw_ * (XV).z; ao.w += pw_ * (XV).w;                              \
    an.x += nw_ * (XV).x; an.y += nw_ * (XV).y;                              \
    an.z += nw_ * (XV).z; an.w += nw_ * (XV).w;                              \
  } while (0)

// ---------------- layer-1 fused: persistent waves, wave per dst ----------------
// Grid-stride over dst nodes: 2048 blocks resident for the whole kernel
// (short-block dispatch fill was ~37%; persistent waves run at the resource cap).
// __launch_bounds__(256,8) pins VGPR<=64 so the cap stays 8 waves/SIMD.
__global__ __launch_bounds__(256, 8) void k_fused1(
    const float* __restrict__ xlr, const float* __restrict__ att,
    const int2* __restrict__ epair,
    const int* __restrict__ starts, const int* __restrict__ counts,
    const int* __restrict__ kptr, const float* __restrict__ bias,
    float* __restrict__ hout, short* __restrict__ nout) {
  __shared__ float sc[4][CAP][4];                 // [wave][edge][head]
  __shared__ __align__(16) ull keys[4][4][72];    // [wave][head][edge], 8-key padded
  int w = threadIdx.x >> 6;
  int l = threadIdx.x & 63;
  int h2 = l >> 5, li = l & 31;
  int headq = li >> 3;
  int hh = l >> 4, ii = l & 15;
  float4 attv = *(const float4*)(att + 4 * li);
  float4 b1v = *(const float4*)(bias + 4 * li);
  int k = kptr[0];

  for (int d = blockIdx.x * 4 + w; d < NN; d += PGRID * 4) {
    int st = starts[d];
    int deg = counts[d];
    if (deg > CAP) deg = CAP;

    int srcreg = 0, idreg = 0x7fffffff;
    if (l < deg) { int2 pe = epair[st + l]; srcreg = pe.x; idreg = pe.y; }
    float4 xrv = *(const float4*)(xlr + (size_t)d * 256 + 128 + 4 * li);

    // ---- scoring: 8-gather burst for rows<16 (register-cached) ----
    float4 xc[8];
    if (deg >= 16) {
      int s_[8];
#pragma unroll
      for (int j = 0; j < 8; j++) s_[j] = __shfl(srcreg, 2 * j + h2);
#pragma unroll
      for (int j = 0; j < 8; j++)
        xc[j] = *(const float4*)(xlr + (size_t)s_[j] * 256 + 4 * li);
      float pp_[8];
#pragma unroll
      for (int j = 0; j < 8; j++) {
        float a_, p_ = 0.f;
        a_ = xc[j].x + xrv.x; p_ += fmaxf(a_, NEG * a_) * attv.x;
        a_ = xc[j].y + xrv.y; p_ += fmaxf(a_, NEG * a_) * attv.y;
        a_ = xc[j].z + xrv.z; p_ += fmaxf(a_, NEG * a_) * attv.z;
        a_ = xc[j].w + xrv.w; p_ += fmaxf(a_, NEG * a_) * attv.w;
        pp_[j] = p_;
      }
#pragma unroll
      for (int o_ = 1; o_ <= 4; o_ <<= 1)
#pragma unroll
        for (int j = 0; j < 8; j++) pp_[j] += __shfl_xor(pp_[j], o_, 64);
      if ((li & 7) == 0) {
#pragma unroll
        for (int j = 0; j < 8; j++) sc[w][2 * j + h2][headq] = pp_[j];
      }
    } else {
      bool v_[8]; int s_[8];
#pragma unroll
      for (int j = 0; j < 8; j++) {
        int r = 2 * j + h2;
        s_[j] = __shfl(srcreg, r);
        v_[j] = r < deg;
      }
#pragma unroll
      for (int j = 0; j < 8; j++) {
        xc[j] = make_float4(0.f, 0.f, 0.f, 0.f);
        if (v_[j]) xc[j] = *(const float4*)(xlr + (size_t)s_[j] * 256 + 4 * li);
      }
      float pp_[8];
#pragma unroll
      for (int j = 0; j < 8; j++) {
        float a_, p_ = 0.f;
        a_ = xc[j].x + xrv.x; p_ += fmaxf(a_, NEG * a_) * attv.x;
        a_ = xc[j].y + xrv.y; p_ += fmaxf(a_, NEG * a_) * attv.y;
        a_ = xc[j].z + xrv.z; p_ += fmaxf(a_, NEG * a_) * attv.z;
        a_ = xc[j].w + xrv.w; p_ += fmaxf(a_, NEG * a_) * attv.w;
        pp_[j] = p_;
      }
#pragma unroll
      for (int o_ = 1; o_ <= 4; o_ <<= 1)
#pragma unroll
        for (int j = 0; j < 8; j++) pp_[j] += __shfl_xor(pp_[j], o_, 64);
      if ((li & 7) == 0) {
#pragma unroll
        for (int j = 0; j < 8; j++)
          if (v_[j]) sc[w][2 * j + h2][headq] = pp_[j];
      }
    }
    for (int q = 16; q < deg; q += 8) {
      if (q + 8 <= deg) SC1_FULL(q);
      else SC1_TAIL(q);
    }

    // ---- top-k via u64-key rank counting (zero-padded, b128-chunked) ----
    float sv[4]; bool val[4]; ull mkey[4];
#pragma unroll
    for (int j = 0; j < 4; j++) {
      int q = j * 16 + ii;
      val[j] = q < deg;
      sv[j] = val[j] ? sc[w][q][hh] : NINF;
      int bid = __shfl(idreg, q);
      mkey[j] = val[j] ? (((ull)fkey(sv[j]) << 32) | (unsigned)~bid) : 0ull;
      if (val[j]) keys[w][hh][q] = mkey[j];
    }
    if (ii < 8) keys[w][hh][deg + ii] = 0ull;  // pad: zero key never outranks
    const ull* kp = keys[w][hh];
    int nch = (deg + 7) >> 3;
    int rk0 = 0, rk1 = 0, rk2 = 0, rk3 = 0;
    if (deg <= 16) {
      for (int c = 0; c < nch; c++) {
        const ull2* p2 = (const ull2*)(kp + c * 8);
        ull2 A_ = p2[0], B_ = p2[1];
        rk0 += (int)(A_[0] > mkey[0]) + (int)(A_[1] > mkey[0]) +
               (int)(B_[0] > mkey[0]) + (int)(B_[1] > mkey[0]);
        ull2 C_ = p2[2], D_ = p2[3];
        rk0 += (int)(C_[0] > mkey[0]) + (int)(C_[1] > mkey[0]) +
               (int)(D_[0] > mkey[0]) + (int)(D_[1] > mkey[0]);
      }
    } else if (deg <= 32) {
      for (int c = 0; c < nch; c++) {
        const ull2* p2 = (const ull2*)(kp + c * 8);
        ull2 A_ = p2[0], B_ = p2[1];
        rk0 += (int)(A_[0] > mkey[0]) + (int)(A_[1] > mkey[0]) +
               (int)(B_[0] > mkey[0]) + (int)(B_[1] > mkey[0]);
        rk1 += (int)(A_[0] > mkey[1]) + (int)(A_[1] > mkey[1]) +
               (int)(B_[0] > mkey[1]) + (int)(B_[1] > mkey[1]);
        ull2 C_ = p2[2], D_ = p2[3];
        rk0 += (int)(C_[0] > mkey[0]) + (int)(C_[1] > mkey[0]) +
               (int)(D_[0] > mkey[0]) + (int)(D_[1] > mkey[0]);
        rk1 += (int)(C_[0] > mkey[1]) + (int)(C_[1] > mkey[1]) +
               (int)(D_[0] > mkey[1]) + (int)(D_[1] > mkey[1]);
      }
    } else {
      for (int c = 0; c < nch; c++) {
        const ull2* p2 = (const ull2*)(kp + c * 8);
        ull2 A_ = p2[0], B_ = p2[1];
        rk0 += (int)(A_[0] > mkey[0]) + (int)(A_[1] > mkey[0]) +
               (int)(B_[0] > mkey[0]) + (int)(B_[1] > mkey[0]);
        rk1 += (int)(A_[0] > mkey[1]) + (int)(A_[1] > mkey[1]) +
               (int)(B_[0] > mkey[1]) + (int)(B_[1] > mkey[1]);
        rk2 += (int)(A_[0] > mkey[2]) + (int)(A_[1] > mkey[2]) +
               (int)(B_[0] > mkey[2]) + (int)(B_[1] > mkey[2]);
        rk3 += (int)(A_[0] > mkey[3]) + (int)(A_[1] > mkey[3]) +
               (int)(B_[0] > mkey[3]) + (int)(B_[1] > mkey[3]);
        ull2 C_ = p2[2], D_ = p2[3];
        rk0 += (int)(C_[0] > mkey[0]) + (int)(C_[1] > mkey[0]) +
               (int)(D_[0] > mkey[0]) + (int)(D_[1] > mkey[0]);
        rk1 += (int)(C_[0] > mkey[1]) + (int)(C_[1] > mkey[1]) +
               (int)(D_[0] > mkey[1]) + (int)(D_[1] > mkey[1]);
        rk2 += (int)(C_[0] > mkey[2]) + (int)(C_[1] > mkey[2]) +
               (int)(D_[0] > mkey[2]) + (int)(D_[1] > mkey[2]);
        rk3 += (int)(C_[0] > mkey[3]) + (int)(C_[1] > mkey[3]) +
               (int)(D_[0] > mkey[3]) + (int)(D_[1] > mkey[3]);
      }
    }
    bool kept[4];
    kept[0] = val[0] && (rk0 < k);
    kept[1] = val[1] && (rk1 < k);
    kept[2] = val[2] && (rk2 < k);
    kept[3] = val[3] && (rk3 < k);

    // ---- dual softmax, no max-shift (scores bounded; exp can't overflow) ----
    float ek[4], en[4], sk = 0.f, sn = 0.f;
#pragma unroll
    for (int j = 0; j < 4; j++) {
      float e_ = __expf(sv[j]);  // exp(NINF) = 0 for invalid lanes
      ek[j] = kept[j] ? e_ : 0.f;
      en[j] = (val[j] && !kept[j]) ? e_ : 0.f;
      sk += ek[j]; sn += en[j];
    }
#pragma unroll
    for (int o = 1; o <= 8; o <<= 1) {
      sk += __shfl_xor(sk, o, 64);
      sn += __shfl_xor(sn, o, 64);
    }
    float ik = 1.f / (sk + 1e-16f), inn = 1.f / (sn + 1e-16f);
#pragma unroll
    for (int j = 0; j < 4; j++) {
      if (val[j]) sc[w][j * 16 + ii][hh] = kept[j] ? ek[j] * ik : -(en[j] * inn);
    }

    // ---- aggregation: rows <16 from registers, tail from global ----
    float4 ao = make_float4(0.f, 0.f, 0.f, 0.f), an = ao;
    if (deg >= 16) {
#pragma unroll
      for (int j = 0; j < 8; j++) {
        float wv = sc[w][2 * j + h2][headq];
        AGG1_FMA(wv, xc[j]);
      }
    } else {
#pragma unroll
      for (int j = 0; j < 8; j++) {
        int r = 2 * j + h2;
        if (r < deg) {
          float wv = sc[w][r][headq];
          AGG1_FMA(wv, xc[j]);
        }
      }
    }
    for (int q = 16; q < deg; q += 8) {
      int s_[4];
#pragma unroll
      for (int j = 0; j < 4; j++) s_[j] = __shfl(srcreg, q + 2 * j + h2);
      if (q + 8 <= deg) {
#pragma unroll
        for (int j = 0; j < 4; j++) {
          float wv = sc[w][q + 2 * j + h2][headq];
          float4 xv = *(const float4*)(xlr + (size_t)s_[j] * 256 + 4 * li);
          AGG1_FMA(wv, xv);
        }
      } else {
#pragma unroll
        for (int j = 0; j < 4; j++) {
          int r = q + 2 * j + h2;
          if (r < deg) {
            float wv = sc[w][r][headq];
            float4 xv = *(const float4*)(xlr + (size_t)s_[j] * 256 + 4 * li);
            AGG1_FMA(wv, xv);
          }
        }
      }
    }
    ao.x += __shfl_xor(ao.x, 32, 64); ao.y += __shfl_xor(ao.y, 32, 64);
    ao.z += __shfl_xor(ao.z, 32, 64); ao.w += __shfl_xor(ao.w, 32, 64);
    an.x += __shfl_xor(an.x, 32, 64); an.y += __shfl_xor(an.y, 32, 64);
    an.z += __shfl_xor(an.z, 32, 64); an.w += __shfl_xor(an.w, 32, 64);
    if (h2 == 0) {
      float4 vo;
      vo.x = ao.x + b1v.x; vo.y = ao.y + b1v.y; vo.z = ao.z + b1v.z; vo.w = ao.w + b1v.w;
      vo.x = vo.x > 0.f ? vo.x : (__expf(vo.x) - 1.f);
      vo.y = vo.y > 0.f ? vo.y : (__expf(vo.y) - 1.f);
      vo.z = vo.z > 0.f ? vo.z : (__expf(vo.z) - 1.f);
      vo.w = vo.w > 0.f ? vo.w : (__expf(vo.w) - 1.f);
      *(float4*)(hout + (size_t)d * D1 + 4 * li) = vo;
    } else {
      short4 vn;
      vn.x = f2bf(an.x + b1v.x); vn.y = f2bf(an.y + b1v.y);
      vn.z = f2bf(an.z + b1v.z); vn.w = f2bf(an.w + b1v.w);
      *(short4*)(nout + (size_t)d * D1 + 4 * li) = vn;
    }
  }
}

// ===== k_fused2 tail helpers (deg>32 only) =====
#define SC2_RED(P0, P1)                                                      \
  _Pragma("unroll") for (int o_ = 1; o_ <= 8; o_ <<= 1) {                    \
    P0 += __shfl_xor(P0, o_, 64);                                            \
    P1 += __shfl_xor(P1, o_, 64);                                            \
  }

#define SC2_FULL(Q)                                                          \
  do {                                                                       \
    int s0_ = __shfl(srcreg, (Q) + g);                                       \
    int s1_ = __shfl(srcreg, (Q) + 4 + g);                                   \
    float x0_ = xlr[(size_t)s0_ * 32 + li];                                  \
    float x1_ = xlr[(size_t)s1_ * 32 + li];                                  \
    float a0_ = x0_ + xrv, a1_ = x1_ + xrv;                                  \
    float p0_ = fmaxf(a0_, NEG * a0_) * attv;                                \
    float p1_ = fmaxf(a1_, NEG * a1_) * attv;                                \
    SC2_RED(p0_, p1_)                                                        \
    if (li == 0) { sc[w][(Q) + g] = p0_; sc[w][(Q) + 4 + g] = p1_; }         \
  } while (0)

#define SC2_TAIL(Q)                                                          \
  do {                                                                       \
    int r0_ = (Q) + g, r1_ = (Q) + 4 + g;                                    \
    int s0_ = __shfl(srcreg, r0_);                                           \
    int s1_ = __shfl(srcreg, r1_);                                           \
    float x0_ = (r0_ < deg) ? xlr[(size_t)s0_ * 32 + li] : 0.f;              \
    float x1_ = (r1_ < deg) ? xlr[(size_t)s1_ * 32 + li] : 0.f;              \
    float a0_ = x0_ + xrv, a1_ = x1_ + xrv;                                  \
    float p0_ = fmaxf(a0_, NEG * a0_) * attv;                                \
    float p1_ = fmaxf(a1_, NEG * a1_) * attv;                                \
    SC2_RED(p0_, p1_)                                                        \
    if (li == 0) {                                                           \
      if (r0_ < deg) sc[w][r0_] = p0_;                                       \
      if (r1_ < deg) sc[w][r1_] = p1_;                                       \
    }                                                                        \
  } while (0)

// ---------------- layer-2 fused: persistent waves ----------------
__global__ __launch_bounds__(256, 8) void k_fused2(
    const float* __restrict__ xlr, const float* __restrict__ att,
    const int2* __restrict__ epair,
    const int* __restrict__ starts, const int* __restrict__ counts,
    const int* __restrict__ kptr, const float* __restrict__ bias,
    float* __restrict__ out0, float* __restrict__ out1) {
  __shared__ float sc[4][CAP];
  __shared__ __align__(16) ull keys[4][72];
  int w = threadIdx.x >> 6;
  int l = threadIdx.x & 63;
  int g = l >> 4, li = l & 15;
  float attv = att[li];
  float bv2 = bias[li];
  int k = kptr[0];

  for (int d = blockIdx.x * 4 + w; d < NN; d += PGRID * 4) {
    int st = starts[d];
    int deg = counts[d];
    if (deg > CAP) deg = CAP;

    int srcreg = 0, idreg = 0x7fffffff;
    if (l < deg) { int2 pe = epair[st + l]; srcreg = pe.x; idreg = pe.y; }
    float xrv = xlr[(size_t)d * 32 + 16 + li];

    // ---- scoring: single gather burst, rows 4j+g (j<8 covers rows<32) ----
    float xc[8];
    {
      bool v_[8]; int s_[8];
#pragma unroll
      for (int j = 0; j < 8; j++) {
        int r = 4 * j + g;
        s_[j] = __shfl(srcreg, r);
        v_[j] = r < deg;
      }
#pragma unroll
      for (int j = 0; j < 8; j++) {
        xc[j] = 0.f;
        if (v_[j]) xc[j] = xlr[(size_t)s_[j] * 32 + li];
      }
      float pp_[8];
#pragma unroll
      for (int j = 0; j < 8; j++) {
        float a_ = xc[j] + xrv;
        pp_[j] = fmaxf(a_, NEG * a_) * attv;
      }
#pragma unroll
      for (int o_ = 1; o_ <= 8; o_ <<= 1)
#pragma unroll
        for (int j = 0; j < 8; j++) pp_[j] += __shfl_xor(pp_[j], o_, 64);
      if (li == 0) {
#pragma unroll
        for (int j = 0; j < 8; j++)
          if (v_[j]) sc[w][4 * j + g] = pp_[j];
      }
    }
    for (int q = 32; q < deg; q += 8) {
      if (q + 8 <= deg) SC2_FULL(q);
      else SC2_TAIL(q);
    }

    // ---- top-k via u64 keys: lane = edge; zero-padded, b128-chunked rank ----
    float sv = (l < deg) ? sc[w][l] : NINF;
    ull mk64 = (l < deg) ? (((ull)fkey(sv) << 32) | (unsigned)~idreg) : 0ull;
    if (l < deg) keys[w][l] = mk64;
    if (l < 8) keys[w][deg + l] = 0ull;
    int rank = 0;
    int nch = (deg + 7) >> 3;
    for (int c = 0; c < nch; c++) {
      const ull2* p2 = (const ull2*)(keys[w] + c * 8);
      ull2 A_ = p2[0], B_ = p2[1];
      rank += (int)(A_[0] > mk64) + (int)(A_[1] > mk64) +
              (int)(B_[0] > mk64) + (int)(B_[1] > mk64);
      ull2 C_ = p2[2], D_ = p2[3];
      rank += (int)(C_[0] > mk64) + (int)(C_[1] > mk64) +
              (int)(D_[0] > mk64) + (int)(D_[1] > mk64);
    }
    bool kept = (l < deg) && (rank < k);

    // ---- dual softmax, no max-shift ----
    float e_ = __expf(sv);
    float ek = kept ? e_ : 0.f;
    float en = ((l < deg) && !kept) ? e_ : 0.f;
    float sk = ek, sn = en;
#pragma unroll
    for (int o = 1; o <= 32; o <<= 1) {
      sk += __shfl_xor(sk, o, 64);
      sn += __shfl_xor(sn, o, 64);
    }
    if (l < deg) sc[w][l] = kept ? ek / (sk + 1e-16f) : -(en / (sn + 1e-16f));

    // ---- aggregation: rows <32 from registers, tail from global ----
    float ao = 0.f, an = 0.f;
    if (deg >= 32) {
#pragma unroll
      for (int j = 0; j < 8; j++) {
        float wv = sc[w][4 * j + g];
        float pw = fmaxf(wv, 0.f), nw = pw - wv;
        ao += pw * xc[j]; an += nw * xc[j];
      }
    } else {
#pragma unroll
      for (int j = 0; j < 8; j++) {
        int r = 4 * j + g;
        if (r < deg) {
          float wv = sc[w][r];
          float pw = fmaxf(wv, 0.f), nw = pw - wv;
          ao += pw * xc[j]; an += nw * xc[j];
        }
      }
    }
    for (int q = 32; q < deg; q += 8) {
      int s0 = __shfl(srcreg, q + g), s1 = __shfl(srcreg, q + 4 + g);
      if (q + 8 <= deg) {
        { float wv = sc[w][q + g];
          float pw = fmaxf(wv, 0.f), nw = pw - wv;
          float xv = xlr[(size_t)s0 * 32 + li];
          ao += pw * xv; an += nw * xv; }
        { float wv = sc[w][q + 4 + g];
          float pw = fmaxf(wv, 0.f), nw = pw - wv;
          float xv = xlr[(size_t)s1 * 32 + li];
          ao += pw * xv; an += nw * xv; }
      } else {
        int r0 = q + g, r1 = q + 4 + g;
        if (r0 < deg) {
          float wv = sc[w][r0];
          float pw = fmaxf(wv, 0.f), nw = pw - wv;
          float xv = xlr[(size_t)s0 * 32 + li];
          ao += pw * xv; an += nw * xv;
        }
        if (r1 < deg) {
          float wv = sc[w][r1];
          float pw = fmaxf(wv, 0.f), nw = pw - wv;
          float xv = xlr[(size_t)s1 * 32 + li];
          ao += pw * xv; an += nw * xv;
        }
      }
    }
    ao += __shfl_xor(ao, 16, 64); ao += __shfl_xor(ao, 32, 64);
    an += __shfl_xor(an, 16, 64); an += __shfl_xor(an, 32, 64);
    float vo = ao + bv2, vn = an + bv2;
    float mo = vo, mv = vn;
#pragma unroll
    for (int o = 1; o <= 8; o <<= 1) {
      mo = fmaxf(mo, __shfl_xor(mo, o, 64));
      mv = fmaxf(mv, __shfl_xor(mv, o, 64));
    }
    float eo = __expf(vo - mo), ev = __expf(vn - mv);
#pragma unroll
    for (int o = 1; o <= 8; o <<= 1) {
      eo += __shfl_xor(eo, o, 64);
      ev += __shfl_xor(ev, o, 64);
    }
    if (g == 0) out0[(size_t)d * NCLS + li] = vo - (mo + logf(eo));
    if (g == 1) out1[(size_t)d * NCLS + li] = vn - (mv + logf(ev));
  }
}

extern "C" void kernel_launch(void* const* d_in, const int* in_sizes, int n_in,
                              void* d_out, int out_size, void* d_ws, size_t ws_size,
                              hipStream_t stream) {
  (void)in_sizes; (void)n_in; (void)out_size; (void)ws_size;
  const float* x    = (const float*)d_in[0];
  const int*   ei   = (const int*)d_in[1];
  const int*   kptr = (const int*)d_in[2];
  const float* Wl1  = (const float*)d_in[3];
  const float* Wr1  = (const float*)d_in[4];
  const float* att1 = (const float*)d_in[5];
  const float* b1   = (const float*)d_in[6];
  const float* Wl2  = (const float*)d_in[7];
  const float* Wr2  = (const float*)d_in[8];
  const float* att2 = (const float*)d_in[9];
  const float* b2   = (const float*)d_in[10];
  const float* l1w  = (const float*)d_in[11];
  const float* l1b  = (const float*)d_in[12];
  const float* l2w  = (const float*)d_in[13];
  const float* l2b  = (const float*)d_in[14];
  const int* srcv = ei;
  const int* dstv = ei + NE;

  char* wp = (char*)d_ws;
  auto alloc = [&](size_t n) { char* p = wp; wp += (n + 255) & ~(size_t)255; return p; };
  float* xlr1   = (float*)alloc((size_t)NN * 256 * 4);  // [NN][256] xl|xr
  float* hbuf   = (float*)alloc((size_t)NN * D1 * 4);   // h = elu(out1+b1)
  short* noise1 = (short*)alloc((size_t)NN * D1 * 2);   // bf16
  short* t1     = (short*)alloc((size_t)NN * D1 * 2);   // mlp hidden, bf16
  float* xlr2   = (float*)alloc((size_t)NN * 32 * 4);   // [NN][32] xl2|xr2
  short* w1t    = (short*)alloc((size_t)128 * 128 * 2); // l1w^T bf16
  short* w2t    = (short*)alloc((size_t)16 * 128 * 2);  // l2w^T bf16
  int* counts = (int*)alloc((size_t)NN * 4);
  int* starts = (int*)alloc((size_t)NN * 4);
  int* cursor = (int*)alloc((size_t)NN * 4);
  int2* epair = (int2*)alloc((size_t)NE * 8);           // packed (src, edge id)
  int* bsum   = (int*)alloc((size_t)NSB * 4);
  int* boff   = (int*)alloc((size_t)NSB * 4);

  // CSR build (by dst) — parallel 3-phase scan
  hipMemsetAsync(counts, 0, (size_t)NN * 4, stream);
  k_count<<<(NE + 255) / 256, 256, 0, stream>>>(dstv, counts);
  k_scanA<<<NSB, 256, 0, stream>>>(counts, bsum);
  k_scanB<<<1, 256, 0, stream>>>(bsum, boff);
  k_scanC<<<NSB, 256, 0, stream>>>(counts, boff, starts, cursor);
  k_scatter<<<(NE + 255) / 256, 256, 0, stream>>>(srcv, dstv, cursor, epair);

  // bf16 weight transpose for the MLP
  k_cvtw<<<64, 256, 0, stream>>>(l1w, l2w, w1t, w2t);

  // Layer 1 node transforms: x @ [Wl1|Wr1] -> xlr1 [NN][256]
  k_gemm2<128, 128, 16, 8, 8, 0><<<dim3(2, (NN + 127) / 128), 256, 0, stream>>>(
      x, Wl1, Wr1, 128, 128, 128, nullptr, xlr1, NN, 256, FIN);

  // Layer 1 fused edge pipeline (persistent waves)
  k_fused1<<<PGRID, 256, 0, stream>>>(xlr1, att1, epair,
                                      starts, counts, kptr, b1, hbuf, noise1);

  float* o = (float*)d_out;

  // MLP on noise1 (bf16 MFMA): t1 = bf16(elu(noise1@l1w+l1b));
  // output1 = log_softmax(t1@l2w+l2b) fused in k_mlp2
  k_mlp1<<<(NN + 63) / 64, 256, 0, stream>>>(noise1, w1t, l1b, t1);
  k_mlp2<<<(NN + 63) / 64, 256, 0, stream>>>(t1, w2t, l2b, o + (size_t)NN * NCLS);

  // Layer 2 node transforms: h @ [Wl2|Wr2] -> xlr2 [NN][32]
  k_gemm2<128, 32, 32, 4, 4, 0><<<dim3(1, (NN + 127) / 128), 256, 0, stream>>>(
      hbuf, Wl2, Wr2, 16, 16, 16, nullptr, xlr2, NN, 32, D1);

  // Layer 2 fused edge pipeline (persistent waves) -> final outputs
  k_fused2<<<PGRID, 256, 0, stream>>>(xlr2, att2, epair, starts,
                                      counts, kptr, b2, o,
                                      o + (size_t)2 * NN * NCLS);
}

// Round 5
// 466.781 us; speedup vs baseline: 1.3327x; 1.3327x over previous
//
#include <hip/hip_runtime.h>
#include <math.h>

#define NN 50000
#define NE 800000
#define FIN 128
#define HEADS 4
#define HID 32
#define D1 128
#define NCLS 16
#define NEG 0.2f
#define NINF (-3.402823466e38f)
#define CAP 64
#define SB 256
#define NSB ((NN + SB - 1) / SB)  // 196
#define PGRID 2048               // persistent grid: 8 blocks/CU x 256 CU

typedef unsigned long long ull;
typedef __attribute__((ext_vector_type(2))) unsigned long long ull2;
typedef __attribute__((ext_vector_type(8))) short bf16x8;
typedef __attribute__((ext_vector_type(4))) float f32x4;

// float -> bf16 bits, round-to-nearest-even
__device__ __forceinline__ short f2bf(float v) {
  unsigned u = __float_as_uint(v);
  unsigned r = (u + 0x7fffu + ((u >> 16) & 1u)) >> 16;
  return (short)r;
}

// ---------------- CSR build ----------------
__global__ void k_count(const int* __restrict__ dst, int* __restrict__ counts) {
  int j = blockIdx.x * 256 + threadIdx.x;
  if (j < NE) atomicAdd(&counts[dst[j]], 1);
}

__global__ void k_scanA(const int* __restrict__ counts, int* __restrict__ bsum) {
  int b = blockIdx.x, t = threadIdx.x;
  int idx = b * SB + t;
  int v = idx < NN ? counts[idx] : 0;
  __shared__ int ws[4];
#pragma unroll
  for (int o = 1; o <= 32; o <<= 1) v += __shfl_xor(v, o, 64);
  if ((t & 63) == 0) ws[t >> 6] = v;
  __syncthreads();
  if (t == 0) bsum[b] = ws[0] + ws[1] + ws[2] + ws[3];
}

__global__ void k_scanB(const int* __restrict__ bsum, int* __restrict__ boff) {
  int t = threadIdx.x;
  int v = t < NSB ? bsum[t] : 0;
  __shared__ int tmp[256];
  tmp[t] = v;
  __syncthreads();
  for (int o = 1; o < 256; o <<= 1) {
    int u = t >= o ? tmp[t - o] : 0;
    __syncthreads();
    tmp[t] += u;
    __syncthreads();
  }
  if (t < NSB) boff[t] = tmp[t] - v;  // exclusive
}

__global__ void k_scanC(const int* __restrict__ counts, const int* __restrict__ boff,
                        int* __restrict__ starts, int* __restrict__ cursor) {
  int b = blockIdx.x, t = threadIdx.x;
  int idx = b * SB + t;
  int v = idx < NN ? counts[idx] : 0;
  __shared__ int tmp[256];
  tmp[t] = v;
  __syncthreads();
  for (int o = 1; o < 256; o <<= 1) {
    int u = t >= o ? tmp[t - o] : 0;
    __syncthreads();
    tmp[t] += u;
    __syncthreads();
  }
  int ex = tmp[t] - v + boff[b];
  if (idx < NN) { starts[idx] = ex; cursor[idx] = ex; }
}

// packed scatter: one 8B write instead of two random 4B writes
__global__ void k_scatter(const int* __restrict__ src, const int* __restrict__ dst,
                          int* __restrict__ cursor, int2* __restrict__ epair) {
  int j = blockIdx.x * 256 + threadIdx.x;
  if (j < NE) {
    int s = src[j];
    int p = atomicAdd(&cursor[dst[j]], 1);
    epair[p] = make_int2(s, j);  // .x = src node, .y = edge id
  }
}

// ---------------- fp32 tiled GEMM, dual-B (cols < N1 from B1, else B2) ----------------
// k-accumulation order is global-k ascending -> bit-identical across tilings.
template <int BM, int BN, int BK, int TM, int TN, int ACT>
__global__ __launch_bounds__(256) void k_gemm2(
    const float* __restrict__ A, const float* __restrict__ B1,
    const float* __restrict__ B2, int N1, int s1, int s2,
    const float* __restrict__ bias, float* __restrict__ C, int M, int N, int K) {
  constexpr int NT = (BM / TM) * (BN / TN);
  static_assert(NT == 256, "block must be 256 threads");
  static_assert(TM % 4 == 0 && TN % 4 == 0, "float4 fragments");
  __shared__ float As[BK][BM + 4];
  __shared__ float Bs[BK][BN];
  int tid = threadIdx.x;
  int bm = blockIdx.y * BM, bn = blockIdx.x * BN;
  constexpr int TX = BN / TN;
  int tn = (tid % TX) * TN;
  int tm = (tid / TX) * TM;
  float acc[TM][TN];
#pragma unroll
  for (int i = 0; i < TM; i++)
#pragma unroll
    for (int j = 0; j < TN; j++) acc[i][j] = 0.f;

  for (int k0 = 0; k0 < K; k0 += BK) {
    constexpr int AV = BM * BK / 4;
    for (int i = tid; i < AV; i += NT) {
      int r = i / (BK / 4);
      int c4 = (i % (BK / 4)) * 4;
      float4 v = make_float4(0.f, 0.f, 0.f, 0.f);
      int gr = bm + r;
      if (gr < M) v = *(const float4*)(A + (size_t)gr * K + k0 + c4);
      As[c4 + 0][r] = v.x; As[c4 + 1][r] = v.y; As[c4 + 2][r] = v.z; As[c4 + 3][r] = v.w;
    }
    constexpr int BV = BK * BN / 4;
    for (int i = tid; i < BV; i += NT) {
      int r = i / (BN / 4), c4 = (i % (BN / 4)) * 4;
      int gc = bn + c4, gk = k0 + r;
      float4 v = (gc < N1) ? *(const float4*)(B1 + (size_t)gk * s1 + gc)
                           : *(const float4*)(B2 + (size_t)gk * s2 + (gc - N1));
      Bs[r][c4 + 0] = v.x; Bs[r][c4 + 1] = v.y; Bs[r][c4 + 2] = v.z; Bs[r][c4 + 3] = v.w;
    }
    __syncthreads();
#pragma unroll
    for (int kk = 0; kk < BK; kk++) {
      float ra[TM], rb[TN];
#pragma unroll
      for (int i = 0; i < TM; i += 4)
        *(float4*)&ra[i] = *(const float4*)&As[kk][tm + i];
#pragma unroll
      for (int j = 0; j < TN; j += 4)
        *(float4*)&rb[j] = *(const float4*)&Bs[kk][tn + j];
#pragma unroll
      for (int i = 0; i < TM; i++)
#pragma unroll
        for (int j = 0; j < TN; j++) acc[i][j] += ra[i] * rb[j];
    }
    __syncthreads();
  }
#pragma unroll
  for (int i = 0; i < TM; i++) {
    int gr = bm + tm + i;
    if (gr >= M) continue;
#pragma unroll
    for (int j = 0; j < TN; j += 4) {
      float4 v;
      v.x = acc[i][j + 0]; v.y = acc[i][j + 1]; v.z = acc[i][j + 2]; v.w = acc[i][j + 3];
      if (bias) {
        v.x += bias[bn + tn + j + 0]; v.y += bias[bn + tn + j + 1];
        v.z += bias[bn + tn + j + 2]; v.w += bias[bn + tn + j + 3];
      }
      if (ACT == 1) {
        v.x = v.x > 0.f ? v.x : (__expf(v.x) - 1.f);
        v.y = v.y > 0.f ? v.y : (__expf(v.y) - 1.f);
        v.z = v.z > 0.f ? v.z : (__expf(v.z) - 1.f);
        v.w = v.w > 0.f ? v.w : (__expf(v.w) - 1.f);
      }
      *(float4*)(C + (size_t)gr * N + bn + tn + j) = v;
    }
  }
}

// ---------------- bf16 weight transpose ----------------
__global__ void k_cvtw(const float* __restrict__ l1w, const float* __restrict__ l2w,
                       short* __restrict__ w1t, short* __restrict__ w2t) {
  int t = blockIdx.x * 256 + threadIdx.x;
  if (t < 128 * 128) {
    int n = t >> 7, k = t & 127;
    w1t[t] = f2bf(l1w[k * 128 + n]);
  }
  if (t < 16 * 128) {
    int n = t >> 7, k = t & 127;
    w2t[t] = f2bf(l2w[k * 16 + n]);
  }
}

// ---------------- MFMA MLP layer 1: C = bf16(elu(A@B + bias)) ----------------
__global__ __launch_bounds__(256) void k_mlp1(
    const short* __restrict__ A, const short* __restrict__ BT,
    const float* __restrict__ bias, short* __restrict__ C) {
  int wv = threadIdx.x >> 6, lane = threadIdx.x & 63;
  int m0 = (blockIdx.x * 4 + wv) * 16;
  int quad = lane >> 4;
  int mr = m0 + (lane & 15);
  bool mok = mr < NN;
  bf16x8 afr[4];
#pragma unroll
  for (int kt = 0; kt < 4; kt++) {
    bf16x8 z = {0, 0, 0, 0, 0, 0, 0, 0};
    afr[kt] = mok ? *(const bf16x8*)(A + (size_t)mr * 128 + kt * 32 + quad * 8) : z;
  }
#pragma unroll
  for (int nt = 0; nt < 8; nt++) {
    f32x4 acc = {0.f, 0.f, 0.f, 0.f};
    int nc = nt * 16 + (lane & 15);
#pragma unroll
    for (int kt = 0; kt < 4; kt++) {
      bf16x8 bfr = *(const bf16x8*)(BT + (size_t)nc * 128 + kt * 32 + quad * 8);
      acc = __builtin_amdgcn_mfma_f32_16x16x32_bf16(afr[kt], bfr, acc, 0, 0, 0);
    }
    float bval = bias[nc];
#pragma unroll
    for (int r = 0; r < 4; r++) {
      int row = m0 + quad * 4 + r;  // C/D: col=lane&15, row=quad*4+reg
      if (row < NN) {
        float v = acc[r] + bval;
        v = v > 0.f ? v : (__expf(v) - 1.f);
        C[(size_t)row * 128 + nc] = f2bf(v);
      }
    }
  }
}

// ---------------- MFMA MLP layer 2 + fused log_softmax ----------------
__global__ __launch_bounds__(256) void k_mlp2(
    const short* __restrict__ A, const short* __restrict__ BT,
    const float* __restrict__ bias, float* __restrict__ out) {
  int wv = threadIdx.x >> 6, lane = threadIdx.x & 63;
  int m0 = (blockIdx.x * 4 + wv) * 16;
  int quad = lane >> 4, col = lane & 15;
  int mr = m0 + col;
  bool mok = mr < NN;
  f32x4 acc = {0.f, 0.f, 0.f, 0.f};
#pragma unroll
  for (int kt = 0; kt < 4; kt++) {
    bf16x8 z = {0, 0, 0, 0, 0, 0, 0, 0};
    bf16x8 afr = mok ? *(const bf16x8*)(A + (size_t)mr * 128 + kt * 32 + quad * 8) : z;
    bf16x8 bfr = *(const bf16x8*)(BT + (size_t)col * 128 + kt * 32 + quad * 8);
    acc = __builtin_amdgcn_mfma_f32_16x16x32_bf16(afr, bfr, acc, 0, 0, 0);
  }
  float bval = bias[col];
#pragma unroll
  for (int r = 0; r < 4; r++) {
    float v = acc[r] + bval;
    float m = v;
#pragma unroll
    for (int o = 1; o <= 8; o <<= 1) m = fmaxf(m, __shfl_xor(m, o, 64));
    float e = __expf(v - m), s = e;
#pragma unroll
    for (int o = 1; o <= 8; o <<= 1) s += __shfl_xor(s, o, 64);
    int row = m0 + quad * 4 + r;
    if (row < NN) out[(size_t)row * NCLS + col] = v - (m + logf(s));
  }
}

// order-preserving float->uint map (lex (score desc,id asc) == u64 desc compare)
__device__ __forceinline__ unsigned fkey(float f) {
  unsigned u = __float_as_uint(f);
  return u ^ (((int)u >> 31) | 0x80000000u);
}

// ===== k_fused1 helpers (tail rows >=16) =====
#define SC1_MACRED()                                                         \
  _Pragma("unroll") for (int j_ = 0; j_ < 4; j_++) {                         \
    float a_, p_ = 0.f;                                                      \
    a_ = xv_[j_].x + xrv.x; p_ += fmaxf(a_, NEG * a_) * attv.x;              \
    a_ = xv_[j_].y + xrv.y; p_ += fmaxf(a_, NEG * a_) * attv.y;              \
    a_ = xv_[j_].z + xrv.z; p_ += fmaxf(a_, NEG * a_) * attv.z;              \
    a_ = xv_[j_].w + xrv.w; p_ += fmaxf(a_, NEG * a_) * attv.w;              \
    pp_[j_] = p_;                                                            \
  }                                                                          \
  _Pragma("unroll") for (int o_ = 1; o_ <= 4; o_ <<= 1)                      \
    _Pragma("unroll") for (int j_ = 0; j_ < 4; j_++)                         \
      pp_[j_] += __shfl_xor(pp_[j_], o_, 64);

#define SC1_FULL(Q)                                                          \
  do {                                                                       \
    int s_[4]; float4 xv_[4]; float pp_[4];                                  \
    _Pragma("unroll") for (int j_ = 0; j_ < 4; j_++)                         \
      s_[j_] = __shfl(srcreg, (Q) + 2 * j_ + h2);                            \
    _Pragma("unroll") for (int j_ = 0; j_ < 4; j_++)                         \
      xv_[j_] = *(const float4*)(xlr + (size_t)s_[j_] * 256 + 4 * li);       \
    SC1_MACRED()                                                             \
    if ((li & 7) == 0) {                                                     \
      _Pragma("unroll") for (int j_ = 0; j_ < 4; j_++)                       \
        sc[w][(Q) + 2 * j_ + h2][headq] = pp_[j_];                           \
    }                                                                        \
  } while (0)

#define SC1_TAIL(Q)                                                          \
  do {                                                                       \
    int s_[4]; float4 xv_[4]; float pp_[4]; bool vv_[4];                     \
    _Pragma("unroll") for (int j_ = 0; j_ < 4; j_++) {                       \
      int r_ = (Q) + 2 * j_ + h2;                                            \
      s_[j_] = __shfl(srcreg, r_);                                           \
      vv_[j_] = r_ < deg;                                                    \
    }                                                                        \
    _Pragma("unroll") for (int j_ = 0; j_ < 4; j_++) {                       \
      xv_[j_] = make_float4(0.f, 0.f, 0.f, 0.f);                             \
      if (vv_[j_])                                                           \
        xv_[j_] = *(const float4*)(xlr + (size_t)s_[j_] * 256 + 4 * li);     \
    }                                                                        \
    SC1_MACRED()                                                             \
    if ((li & 7) == 0) {                                                     \
      _Pragma("unroll") for (int j_ = 0; j_ < 4; j_++)                       \
        if (vv_[j_]) sc[w][(Q) + 2 * j_ + h2][headq] = pp_[j_];              \
    }                                                                        \
  } while (0)

#define AGG1_FMA(WV, XV)                                                     \
  do {                                                                       \
    float pw_ = fmaxf((WV), 0.f), nw_ = pw_ - (WV);                          \
    ao.x += pw_ * (XV).x; ao.y += pw_ * (XV).y;                              \
    ao.z += pw_ * (XV).z; ao.w += pw_ * (XV).w;                              \
    an.x += nw_ * (XV).x; an.y += nw_ * (XV).y;                              \
    an.z += nw_ * (XV).z; an.w += nw_ * (XV).w;                              \
  } while (0)

// ---------------- layer-1 fused: persistent waves, wave per dst ----------------
// Grid-stride over dst nodes: 2048 blocks resident for the whole kernel
// (r4 proved persistent waves lift occupancy 36->82%). NO min-waves pin:
// r4's (256,8) pin forced VGPR 56->32 and spilled ~1GB scratch to HBM.
// Natural allocation is ~56 VGPR (r2) <= 64, so 8 blocks/CU still fit.
__global__ __launch_bounds__(256) void k_fused1(
    const float* __restrict__ xlr, const float* __restrict__ att,
    const int2* __restrict__ epair,
    const int* __restrict__ starts, const int* __restrict__ counts,
    const int* __restrict__ kptr, const float* __restrict__ bias,
    float* __restrict__ hout, short* __restrict__ nout) {
  __shared__ float sc[4][CAP][4];                 // [wave][edge][head]
  __shared__ __align__(16) ull keys[4][4][72];    // [wave][head][edge], 8-key padded
  int w = threadIdx.x >> 6;
  int l = threadIdx.x & 63;
  int h2 = l >> 5, li = l & 31;
  int headq = li >> 3;
  int hh = l >> 4, ii = l & 15;
  float4 attv = *(const float4*)(att + 4 * li);
  float4 b1v = *(const float4*)(bias + 4 * li);
  int k = kptr[0];

  for (int d = blockIdx.x * 4 + w; d < NN; d += PGRID * 4) {
    int st = starts[d];
    int deg = counts[d];
    if (deg > CAP) deg = CAP;

    int srcreg = 0, idreg = 0x7fffffff;
    if (l < deg) { int2 pe = epair[st + l]; srcreg = pe.x; idreg = pe.y; }
    float4 xrv = *(const float4*)(xlr + (size_t)d * 256 + 128 + 4 * li);

    // ---- scoring: 8-gather burst for rows<16 (register-cached) ----
    float4 xc[8];
    if (deg >= 16) {
      int s_[8];
#pragma unroll
      for (int j = 0; j < 8; j++) s_[j] = __shfl(srcreg, 2 * j + h2);
#pragma unroll
      for (int j = 0; j < 8; j++)
        xc[j] = *(const float4*)(xlr + (size_t)s_[j] * 256 + 4 * li);
      float pp_[8];
#pragma unroll
      for (int j = 0; j < 8; j++) {
        float a_, p_ = 0.f;
        a_ = xc[j].x + xrv.x; p_ += fmaxf(a_, NEG * a_) * attv.x;
        a_ = xc[j].y + xrv.y; p_ += fmaxf(a_, NEG * a_) * attv.y;
        a_ = xc[j].z + xrv.z; p_ += fmaxf(a_, NEG * a_) * attv.z;
        a_ = xc[j].w + xrv.w; p_ += fmaxf(a_, NEG * a_) * attv.w;
        pp_[j] = p_;
      }
#pragma unroll
      for (int o_ = 1; o_ <= 4; o_ <<= 1)
#pragma unroll
        for (int j = 0; j < 8; j++) pp_[j] += __shfl_xor(pp_[j], o_, 64);
      if ((li & 7) == 0) {
#pragma unroll
        for (int j = 0; j < 8; j++) sc[w][2 * j + h2][headq] = pp_[j];
      }
    } else {
      bool v_[8]; int s_[8];
#pragma unroll
      for (int j = 0; j < 8; j++) {
        int r = 2 * j + h2;
        s_[j] = __shfl(srcreg, r);
        v_[j] = r < deg;
      }
#pragma unroll
      for (int j = 0; j < 8; j++) {
        xc[j] = make_float4(0.f, 0.f, 0.f, 0.f);
        if (v_[j]) xc[j] = *(const float4*)(xlr + (size_t)s_[j] * 256 + 4 * li);
      }
      float pp_[8];
#pragma unroll
      for (int j = 0; j < 8; j++) {
        float a_, p_ = 0.f;
        a_ = xc[j].x + xrv.x; p_ += fmaxf(a_, NEG * a_) * attv.x;
        a_ = xc[j].y + xrv.y; p_ += fmaxf(a_, NEG * a_) * attv.y;
        a_ = xc[j].z + xrv.z; p_ += fmaxf(a_, NEG * a_) * attv.z;
        a_ = xc[j].w + xrv.w; p_ += fmaxf(a_, NEG * a_) * attv.w;
        pp_[j] = p_;
      }
#pragma unroll
      for (int o_ = 1; o_ <= 4; o_ <<= 1)
#pragma unroll
        for (int j = 0; j < 8; j++) pp_[j] += __shfl_xor(pp_[j], o_, 64);
      if ((li & 7) == 0) {
#pragma unroll
        for (int j = 0; j < 8; j++)
          if (v_[j]) sc[w][2 * j + h2][headq] = pp_[j];
      }
    }
    for (int q = 16; q < deg; q += 8) {
      if (q + 8 <= deg) SC1_FULL(q);
      else SC1_TAIL(q);
    }

    // ---- top-k via u64-key rank counting (zero-padded, b128-chunked) ----
    float sv[4]; bool val[4]; ull mkey[4];
#pragma unroll
    for (int j = 0; j < 4; j++) {
      int q = j * 16 + ii;
      val[j] = q < deg;
      sv[j] = val[j] ? sc[w][q][hh] : NINF;
      int bid = __shfl(idreg, q);
      mkey[j] = val[j] ? (((ull)fkey(sv[j]) << 32) | (unsigned)~bid) : 0ull;
      if (val[j]) keys[w][hh][q] = mkey[j];
    }
    if (ii < 8) keys[w][hh][deg + ii] = 0ull;  // pad: zero key never outranks
    const ull* kp = keys[w][hh];
    int nch = (deg + 7) >> 3;
    int rk0 = 0, rk1 = 0, rk2 = 0, rk3 = 0;
    if (deg <= 16) {
      for (int c = 0; c < nch; c++) {
        const ull2* p2 = (const ull2*)(kp + c * 8);
        ull2 A_ = p2[0], B_ = p2[1];
        rk0 += (int)(A_[0] > mkey[0]) + (int)(A_[1] > mkey[0]) +
               (int)(B_[0] > mkey[0]) + (int)(B_[1] > mkey[0]);
        ull2 C_ = p2[2], D_ = p2[3];
        rk0 += (int)(C_[0] > mkey[0]) + (int)(C_[1] > mkey[0]) +
               (int)(D_[0] > mkey[0]) + (int)(D_[1] > mkey[0]);
      }
    } else if (deg <= 32) {
      for (int c = 0; c < nch; c++) {
        const ull2* p2 = (const ull2*)(kp + c * 8);
        ull2 A_ = p2[0], B_ = p2[1];
        rk0 += (int)(A_[0] > mkey[0]) + (int)(A_[1] > mkey[0]) +
               (int)(B_[0] > mkey[0]) + (int)(B_[1] > mkey[0]);
        rk1 += (int)(A_[0] > mkey[1]) + (int)(A_[1] > mkey[1]) +
               (int)(B_[0] > mkey[1]) + (int)(B_[1] > mkey[1]);
        ull2 C_ = p2[2], D_ = p2[3];
        rk0 += (int)(C_[0] > mkey[0]) + (int)(C_[1] > mkey[0]) +
               (int)(D_[0] > mkey[0]) + (int)(D_[1] > mkey[0]);
        rk1 += (int)(C_[0] > mkey[1]) + (int)(C_[1] > mkey[1]) +
               (int)(D_[0] > mkey[1]) + (int)(D_[1] > mkey[1]);
      }
    } else {
      for (int c = 0; c < nch; c++) {
        const ull2* p2 = (const ull2*)(kp + c * 8);
        ull2 A_ = p2[0], B_ = p2[1];
        rk0 += (int)(A_[0] > mkey[0]) + (int)(A_[1] > mkey[0]) +
               (int)(B_[0] > mkey[0]) + (int)(B_[1] > mkey[0]);
        rk1 += (int)(A_[0] > mkey[1]) + (int)(A_[1] > mkey[1]) +
               (int)(B_[0] > mkey[1]) + (int)(B_[1] > mkey[1]);
        rk2 += (int)(A_[0] > mkey[2]) + (int)(A_[1] > mkey[2]) +
               (int)(B_[0] > mkey[2]) + (int)(B_[1] > mkey[2]);
        rk3 += (int)(A_[0] > mkey[3]) + (int)(A_[1] > mkey[3]) +
               (int)(B_[0] > mkey[3]) + (int)(B_[1] > mkey[3]);
        ull2 C_ = p2[2], D_ = p2[3];
        rk0 += (int)(C_[0] > mkey[0]) + (int)(C_[1] > mkey[0]) +
               (int)(D_[0] > mkey[0]) + (int)(D_[1] > mkey[0]);
        rk1 += (int)(C_[0] > mkey[1]) + (int)(C_[1] > mkey[1]) +
               (int)(D_[0] > mkey[1]) + (int)(D_[1] > mkey[1]);
        rk2 += (int)(C_[0] > mkey[2]) + (int)(C_[1] > mkey[2]) +
               (int)(D_[0] > mkey[2]) + (int)(D_[1] > mkey[2]);
        rk3 += (int)(C_[0] > mkey[3]) + (int)(C_[1] > mkey[3]) +
               (int)(D_[0] > mkey[3]) + (int)(D_[1] > mkey[3]);
      }
    }
    bool kept[4];
    kept[0] = val[0] && (rk0 < k);
    kept[1] = val[1] && (rk1 < k);
    kept[2] = val[2] && (rk2 < k);
    kept[3] = val[3] && (rk3 < k);

    // ---- dual softmax, no max-shift (scores bounded; exp can't overflow) ----
    float ek[4], en[4], sk = 0.f, sn = 0.f;
#pragma unroll
    for (int j = 0; j < 4; j++) {
      float e_ = __expf(sv[j]);  // exp(NINF) = 0 for invalid lanes
      ek[j] = kept[j] ? e_ : 0.f;
      en[j] = (val[j] && !kept[j]) ? e_ : 0.f;
      sk += ek[j]; sn += en[j];
    }
#pragma unroll
    for (int o = 1; o <= 8; o <<= 1) {
      sk += __shfl_xor(sk, o, 64);
      sn += __shfl_xor(sn, o, 64);
    }
    float ik = 1.f / (sk + 1e-16f), inn = 1.f / (sn + 1e-16f);
#pragma unroll
    for (int j = 0; j < 4; j++) {
      if (val[j]) sc[w][j * 16 + ii][hh] = kept[j] ? ek[j] * ik : -(en[j] * inn);
    }

    // ---- aggregation: rows <16 from registers, tail from global ----
    float4 ao = make_float4(0.f, 0.f, 0.f, 0.f), an = ao;
    if (deg >= 16) {
#pragma unroll
      for (int j = 0; j < 8; j++) {
        float wv = sc[w][2 * j + h2][headq];
        AGG1_FMA(wv, xc[j]);
      }
    } else {
#pragma unroll
      for (int j = 0; j < 8; j++) {
        int r = 2 * j + h2;
        if (r < deg) {
          float wv = sc[w][r][headq];
          AGG1_FMA(wv, xc[j]);
        }
      }
    }
    for (int q = 16; q < deg; q += 8) {
      int s_[4];
#pragma unroll
      for (int j = 0; j < 4; j++) s_[j] = __shfl(srcreg, q + 2 * j + h2);
      if (q + 8 <= deg) {
#pragma unroll
        for (int j = 0; j < 4; j++) {
          float wv = sc[w][q + 2 * j + h2][headq];
          float4 xv = *(const float4*)(xlr + (size_t)s_[j] * 256 + 4 * li);
          AGG1_FMA(wv, xv);
        }
      } else {
#pragma unroll
        for (int j = 0; j < 4; j++) {
          int r = q + 2 * j + h2;
          if (r < deg) {
            float wv = sc[w][r][headq];
            float4 xv = *(const float4*)(xlr + (size_t)s_[j] * 256 + 4 * li);
            AGG1_FMA(wv, xv);
          }
        }
      }
    }
    ao.x += __shfl_xor(ao.x, 32, 64); ao.y += __shfl_xor(ao.y, 32, 64);
    ao.z += __shfl_xor(ao.z, 32, 64); ao.w += __shfl_xor(ao.w, 32, 64);
    an.x += __shfl_xor(an.x, 32, 64); an.y += __shfl_xor(an.y, 32, 64);
    an.z += __shfl_xor(an.z, 32, 64); an.w += __shfl_xor(an.w, 32, 64);
    if (h2 == 0) {
      float4 vo;
      vo.x = ao.x + b1v.x; vo.y = ao.y + b1v.y; vo.z = ao.z + b1v.z; vo.w = ao.w + b1v.w;
      vo.x = vo.x > 0.f ? vo.x : (__expf(vo.x) - 1.f);
      vo.y = vo.y > 0.f ? vo.y : (__expf(vo.y) - 1.f);
      vo.z = vo.z > 0.f ? vo.z : (__expf(vo.z) - 1.f);
      vo.w = vo.w > 0.f ? vo.w : (__expf(vo.w) - 1.f);
      *(float4*)(hout + (size_t)d * D1 + 4 * li) = vo;
    } else {
      short4 vn;
      vn.x = f2bf(an.x + b1v.x); vn.y = f2bf(an.y + b1v.y);
      vn.z = f2bf(an.z + b1v.z); vn.w = f2bf(an.w + b1v.w);
      *(short4*)(nout + (size_t)d * D1 + 4 * li) = vn;
    }
  }
}

// ===== k_fused2 tail helpers (deg>32 only) =====
#define SC2_RED(P0, P1)                                                      \
  _Pragma("unroll") for (int o_ = 1; o_ <= 8; o_ <<= 1) {                    \
    P0 += __shfl_xor(P0, o_, 64);                                            \
    P1 += __shfl_xor(P1, o_, 64);                                            \
  }

#define SC2_FULL(Q)                                                          \
  do {                                                                       \
    int s0_ = __shfl(srcreg, (Q) + g);                                       \
    int s1_ = __shfl(srcreg, (Q) + 4 + g);                                   \
    float x0_ = xlr[(size_t)s0_ * 32 + li];                                  \
    float x1_ = xlr[(size_t)s1_ * 32 + li];                                  \
    float a0_ = x0_ + xrv, a1_ = x1_ + xrv;                                  \
    float p0_ = fmaxf(a0_, NEG * a0_) * attv;                                \
    float p1_ = fmaxf(a1_, NEG * a1_) * attv;                                \
    SC2_RED(p0_, p1_)                                                        \
    if (li == 0) { sc[w][(Q) + g] = p0_; sc[w][(Q) + 4 + g] = p1_; }         \
  } while (0)

#define SC2_TAIL(Q)                                                          \
  do {                                                                       \
    int r0_ = (Q) + g, r1_ = (Q) + 4 + g;                                    \
    int s0_ = __shfl(srcreg, r0_);                                           \
    int s1_ = __shfl(srcreg, r1_);                                           \
    float x0_ = (r0_ < deg) ? xlr[(size_t)s0_ * 32 + li] : 0.f;              \
    float x1_ = (r1_ < deg) ? xlr[(size_t)s1_ * 32 + li] : 0.f;              \
    float a0_ = x0_ + xrv, a1_ = x1_ + xrv;                                  \
    float p0_ = fmaxf(a0_, NEG * a0_) * attv;                                \
    float p1_ = fmaxf(a1_, NEG * a1_) * attv;                                \
    SC2_RED(p0_, p1_)                                                        \
    if (li == 0) {                                                           \
      if (r0_ < deg) sc[w][r0_] = p0_;                                       \
      if (r1_ < deg) sc[w][r1_] = p1_;                                       \
    }                                                                        \
  } while (0)

// ---------------- layer-2 fused: persistent waves ----------------
__global__ __launch_bounds__(256) void k_fused2(
    const float* __restrict__ xlr, const float* __restrict__ att,
    const int2* __restrict__ epair,
    const int* __restrict__ starts, const int* __restrict__ counts,
    const int* __restrict__ kptr, const float* __restrict__ bias,
    float* __restrict__ out0, float* __restrict__ out1) {
  __shared__ float sc[4][CAP];
  __shared__ __align__(16) ull keys[4][72];
  int w = threadIdx.x >> 6;
  int l = threadIdx.x & 63;
  int g = l >> 4, li = l & 15;
  float attv = att[li];
  float bv2 = bias[li];
  int k = kptr[0];

  for (int d = blockIdx.x * 4 + w; d < NN; d += PGRID * 4) {
    int st = starts[d];
    int deg = counts[d];
    if (deg > CAP) deg = CAP;

    int srcreg = 0, idreg = 0x7fffffff;
    if (l < deg) { int2 pe = epair[st + l]; srcreg = pe.x; idreg = pe.y; }
    float xrv = xlr[(size_t)d * 32 + 16 + li];

    // ---- scoring: single gather burst, rows 4j+g (j<8 covers rows<32) ----
    float xc[8];
    {
      bool v_[8]; int s_[8];
#pragma unroll
      for (int j = 0; j < 8; j++) {
        int r = 4 * j + g;
        s_[j] = __shfl(srcreg, r);
        v_[j] = r < deg;
      }
#pragma unroll
      for (int j = 0; j < 8; j++) {
        xc[j] = 0.f;
        if (v_[j]) xc[j] = xlr[(size_t)s_[j] * 32 + li];
      }
      float pp_[8];
#pragma unroll
      for (int j = 0; j < 8; j++) {
        float a_ = xc[j] + xrv;
        pp_[j] = fmaxf(a_, NEG * a_) * attv;
      }
#pragma unroll
      for (int o_ = 1; o_ <= 8; o_ <<= 1)
#pragma unroll
        for (int j = 0; j < 8; j++) pp_[j] += __shfl_xor(pp_[j], o_, 64);
      if (li == 0) {
#pragma unroll
        for (int j = 0; j < 8; j++)
          if (v_[j]) sc[w][4 * j + g] = pp_[j];
      }
    }
    for (int q = 32; q < deg; q += 8) {
      if (q + 8 <= deg) SC2_FULL(q);
      else SC2_TAIL(q);
    }

    // ---- top-k via u64 keys: lane = edge; zero-padded, b128-chunked rank ----
    float sv = (l < deg) ? sc[w][l] : NINF;
    ull mk64 = (l < deg) ? (((ull)fkey(sv) << 32) | (unsigned)~idreg) : 0ull;
    if (l < deg) keys[w][l] = mk64;
    if (l < 8) keys[w][deg + l] = 0ull;
    int rank = 0;
    int nch = (deg + 7) >> 3;
    for (int c = 0; c < nch; c++) {
      const ull2* p2 = (const ull2*)(keys[w] + c * 8);
      ull2 A_ = p2[0], B_ = p2[1];
      rank += (int)(A_[0] > mk64) + (int)(A_[1] > mk64) +
              (int)(B_[0] > mk64) + (int)(B_[1] > mk64);
      ull2 C_ = p2[2], D_ = p2[3];
      rank += (int)(C_[0] > mk64) + (int)(C_[1] > mk64) +
              (int)(D_[0] > mk64) + (int)(D_[1] > mk64);
    }
    bool kept = (l < deg) && (rank < k);

    // ---- dual softmax, no max-shift ----
    float e_ = __expf(sv);
    float ek = kept ? e_ : 0.f;
    float en = ((l < deg) && !kept) ? e_ : 0.f;
    float sk = ek, sn = en;
#pragma unroll
    for (int o = 1; o <= 32; o <<= 1) {
      sk += __shfl_xor(sk, o, 64);
      sn += __shfl_xor(sn, o, 64);
    }
    if (l < deg) sc[w][l] = kept ? ek / (sk + 1e-16f) : -(en / (sn + 1e-16f));

    // ---- aggregation: rows <32 from registers, tail from global ----
    float ao = 0.f, an = 0.f;
    if (deg >= 32) {
#pragma unroll
      for (int j = 0; j < 8; j++) {
        float wv = sc[w][4 * j + g];
        float pw = fmaxf(wv, 0.f), nw = pw - wv;
        ao += pw * xc[j]; an += nw * xc[j];
      }
    } else {
#pragma unroll
      for (int j = 0; j < 8; j++) {
        int r = 4 * j + g;
        if (r < deg) {
          float wv = sc[w][r];
          float pw = fmaxf(wv, 0.f), nw = pw - wv;
          ao += pw * xc[j]; an += nw * xc[j];
        }
      }
    }
    for (int q = 32; q < deg; q += 8) {
      int s0 = __shfl(srcreg, q + g), s1 = __shfl(srcreg, q + 4 + g);
      if (q + 8 <= deg) {
        { float wv = sc[w][q + g];
          float pw = fmaxf(wv, 0.f), nw = pw - wv;
          float xv = xlr[(size_t)s0 * 32 + li];
          ao += pw * xv; an += nw * xv; }
        { float wv = sc[w][q + 4 + g];
          float pw = fmaxf(wv, 0.f), nw = pw - wv;
          float xv = xlr[(size_t)s1 * 32 + li];
          ao += pw * xv; an += nw * xv; }
      } else {
        int r0 = q + g, r1 = q + 4 + g;
        if (r0 < deg) {
          float wv = sc[w][r0];
          float pw = fmaxf(wv, 0.f), nw = pw - wv;
          float xv = xlr[(size_t)s0 * 32 + li];
          ao += pw * xv; an += nw * xv;
        }
        if (r1 < deg) {
          float wv = sc[w][r1];
          float pw = fmaxf(wv, 0.f), nw = pw - wv;
          float xv = xlr[(size_t)s1 * 32 + li];
          ao += pw * xv; an += nw * xv;
        }
      }
    }
    ao += __shfl_xor(ao, 16, 64); ao += __shfl_xor(ao, 32, 64);
    an += __shfl_xor(an, 16, 64); an += __shfl_xor(an, 32, 64);
    float vo = ao + bv2, vn = an + bv2;
    float mo = vo, mv = vn;
#pragma unroll
    for (int o = 1; o <= 8; o <<= 1) {
      mo = fmaxf(mo, __shfl_xor(mo, o, 64));
      mv = fmaxf(mv, __shfl_xor(mv, o, 64));
    }
    float eo = __expf(vo - mo), ev = __expf(vn - mv);
#pragma unroll
    for (int o = 1; o <= 8; o <<= 1) {
      eo += __shfl_xor(eo, o, 64);
      ev += __shfl_xor(ev, o, 64);
    }
    if (g == 0) out0[(size_t)d * NCLS + li] = vo - (mo + logf(eo));
    if (g == 1) out1[(size_t)d * NCLS + li] = vn - (mv + logf(ev));
  }
}

extern "C" void kernel_launch(void* const* d_in, const int* in_sizes, int n_in,
                              void* d_out, int out_size, void* d_ws, size_t ws_size,
                              hipStream_t stream) {
  (void)in_sizes; (void)n_in; (void)out_size; (void)ws_size;
  const float* x    = (const float*)d_in[0];
  const int*   ei   = (const int*)d_in[1];
  const int*   kptr = (const int*)d_in[2];
  const float* Wl1  = (const float*)d_in[3];
  const float* Wr1  = (const float*)d_in[4];
  const float* att1 = (const float*)d_in[5];
  const float* b1   = (const float*)d_in[6];
  const float* Wl2  = (const float*)d_in[7];
  const float* Wr2  = (const float*)d_in[8];
  const float* att2 = (const float*)d_in[9];
  const float* b2   = (const float*)d_in[10];
  const float* l1w  = (const float*)d_in[11];
  const float* l1b  = (const float*)d_in[12];
  const float* l2w  = (const float*)d_in[13];
  const float* l2b  = (const float*)d_in[14];
  const int* srcv = ei;
  const int* dstv = ei + NE;

  char* wp = (char*)d_ws;
  auto alloc = [&](size_t n) { char* p = wp; wp += (n + 255) & ~(size_t)255; return p; };
  float* xlr1   = (float*)alloc((size_t)NN * 256 * 4);  // [NN][256] xl|xr
  float* hbuf   = (float*)alloc((size_t)NN * D1 * 4);   // h = elu(out1+b1)
  short* noise1 = (short*)alloc((size_t)NN * D1 * 2);   // bf16
  short* t1     = (short*)alloc((size_t)NN * D1 * 2);   // mlp hidden, bf16
  float* xlr2   = (float*)alloc((size_t)NN * 32 * 4);   // [NN][32] xl2|xr2
  short* w1t    = (short*)alloc((size_t)128 * 128 * 2); // l1w^T bf16
  short* w2t    = (short*)alloc((size_t)16 * 128 * 2);  // l2w^T bf16
  int* counts = (int*)alloc((size_t)NN * 4);
  int* starts = (int*)alloc((size_t)NN * 4);
  int* cursor = (int*)alloc((size_t)NN * 4);
  int2* epair = (int2*)alloc((size_t)NE * 8);           // packed (src, edge id)
  int* bsum   = (int*)alloc((size_t)NSB * 4);
  int* boff   = (int*)alloc((size_t)NSB * 4);

  // CSR build (by dst) — parallel 3-phase scan
  hipMemsetAsync(counts, 0, (size_t)NN * 4, stream);
  k_count<<<(NE + 255) / 256, 256, 0, stream>>>(dstv, counts);
  k_scanA<<<NSB, 256, 0, stream>>>(counts, bsum);
  k_scanB<<<1, 256, 0, stream>>>(bsum, boff);
  k_scanC<<<NSB, 256, 0, stream>>>(counts, boff, starts, cursor);
  k_scatter<<<(NE + 255) / 256, 256, 0, stream>>>(srcv, dstv, cursor, epair);

  // bf16 weight transpose for the MLP
  k_cvtw<<<64, 256, 0, stream>>>(l1w, l2w, w1t, w2t);

  // Layer 1 node transforms: x @ [Wl1|Wr1] -> xlr1 [NN][256]
  k_gemm2<128, 128, 16, 8, 8, 0><<<dim3(2, (NN + 127) / 128), 256, 0, stream>>>(
      x, Wl1, Wr1, 128, 128, 128, nullptr, xlr1, NN, 256, FIN);

  // Layer 1 fused edge pipeline (persistent waves)
  k_fused1<<<PGRID, 256, 0, stream>>>(xlr1, att1, epair,
                                      starts, counts, kptr, b1, hbuf, noise1);

  float* o = (float*)d_out;

  // MLP on noise1 (bf16 MFMA): t1 = bf16(elu(noise1@l1w+l1b));
  // output1 = log_softmax(t1@l2w+l2b) fused in k_mlp2
  k_mlp1<<<(NN + 63) / 64, 256, 0, stream>>>(noise1, w1t, l1b, t1);
  k_mlp2<<<(NN + 63) / 64, 256, 0, stream>>>(t1, w2t, l2b, o + (size_t)NN * NCLS);

  // Layer 2 node transforms: h @ [Wl2|Wr2] -> xlr2 [NN][32]
  k_gemm2<128, 32, 32, 4, 4, 0><<<dim3(1, (NN + 127) / 128), 256, 0, stream>>>(
      hbuf, Wl2, Wr2, 16, 16, 16, nullptr, xlr2, NN, 32, D1);

  // Layer 2 fused edge pipeline (persistent waves) -> final outputs
  k_fused2<<<PGRID, 256, 0, stream>>>(xlr2, att2, epair, starts,
                                      counts, kptr, b2, o,
                                      o + (size_t)2 * NN * NCLS);
}

// Round 6
// 432.098 us; speedup vs baseline: 1.4397x; 1.0803x over previous
//
#include <hip/hip_runtime.h>
#include <math.h>

#define NN 50000
#define NE 800000
#define FIN 128
#define HEADS 4
#define HID 32
#define D1 128
#define NCLS 16
#define NEG 0.2f
#define NINF (-3.402823466e38f)
#define CAP 64
#define SB 256
#define NSB ((NN + SB - 1) / SB)  // 196

typedef unsigned long long ull;
typedef __attribute__((ext_vector_type(2))) unsigned long long ull2;
typedef __attribute__((ext_vector_type(8))) short bf16x8;
typedef __attribute__((ext_vector_type(4))) float f32x4;

// float -> bf16 bits, round-to-nearest-even
__device__ __forceinline__ short f2bf(float v) {
  unsigned u = __float_as_uint(v);
  unsigned r = (u + 0x7fffu + ((u >> 16) & 1u)) >> 16;
  return (short)r;
}

// ---------------- CSR build ----------------
__global__ void k_count(const int* __restrict__ dst, int* __restrict__ counts) {
  int j = blockIdx.x * 256 + threadIdx.x;
  if (j < NE) atomicAdd(&counts[dst[j]], 1);
}

__global__ void k_scanA(const int* __restrict__ counts, int* __restrict__ bsum) {
  int b = blockIdx.x, t = threadIdx.x;
  int idx = b * SB + t;
  int v = idx < NN ? counts[idx] : 0;
  __shared__ int ws[4];
#pragma unroll
  for (int o = 1; o <= 32; o <<= 1) v += __shfl_xor(v, o, 64);
  if ((t & 63) == 0) ws[t >> 6] = v;
  __syncthreads();
  if (t == 0) bsum[b] = ws[0] + ws[1] + ws[2] + ws[3];
}

__global__ void k_scanB(const int* __restrict__ bsum, int* __restrict__ boff) {
  int t = threadIdx.x;
  int v = t < NSB ? bsum[t] : 0;
  __shared__ int tmp[256];
  tmp[t] = v;
  __syncthreads();
  for (int o = 1; o < 256; o <<= 1) {
    int u = t >= o ? tmp[t - o] : 0;
    __syncthreads();
    tmp[t] += u;
    __syncthreads();
  }
  if (t < NSB) boff[t] = tmp[t] - v;  // exclusive
}

__global__ void k_scanC(const int* __restrict__ counts, const int* __restrict__ boff,
                        int* __restrict__ starts, int* __restrict__ cursor) {
  int b = blockIdx.x, t = threadIdx.x;
  int idx = b * SB + t;
  int v = idx < NN ? counts[idx] : 0;
  __shared__ int tmp[256];
  tmp[t] = v;
  __syncthreads();
  for (int o = 1; o < 256; o <<= 1) {
    int u = t >= o ? tmp[t - o] : 0;
    __syncthreads();
    tmp[t] += u;
    __syncthreads();
  }
  int ex = tmp[t] - v + boff[b];
  if (idx < NN) { starts[idx] = ex; cursor[idx] = ex; }
}

// packed scatter: one 8B write instead of two random 4B writes
__global__ void k_scatter(const int* __restrict__ src, const int* __restrict__ dst,
                          int* __restrict__ cursor, int2* __restrict__ epair) {
  int j = blockIdx.x * 256 + threadIdx.x;
  if (j < NE) {
    int s = src[j];
    int p = atomicAdd(&cursor[dst[j]], 1);
    epair[p] = make_int2(s, j);  // .x = src node, .y = edge id
  }
}

// ---------------- fp32 tiled GEMM, dual-B (cols < N1 from B1, else B2) ----------------
// k-accumulation order is global-k ascending -> bit-identical across tilings.
template <int BM, int BN, int BK, int TM, int TN, int ACT>
__global__ __launch_bounds__(256) void k_gemm2(
    const float* __restrict__ A, const float* __restrict__ B1,
    const float* __restrict__ B2, int N1, int s1, int s2,
    const float* __restrict__ bias, float* __restrict__ C, int M, int N, int K) {
  constexpr int NT = (BM / TM) * (BN / TN);
  static_assert(NT == 256, "block must be 256 threads");
  static_assert(TM % 4 == 0 && TN % 4 == 0, "float4 fragments");
  __shared__ float As[BK][BM + 4];
  __shared__ float Bs[BK][BN];
  int tid = threadIdx.x;
  int bm = blockIdx.y * BM, bn = blockIdx.x * BN;
  constexpr int TX = BN / TN;
  int tn = (tid % TX) * TN;
  int tm = (tid / TX) * TM;
  float acc[TM][TN];
#pragma unroll
  for (int i = 0; i < TM; i++)
#pragma unroll
    for (int j = 0; j < TN; j++) acc[i][j] = 0.f;

  for (int k0 = 0; k0 < K; k0 += BK) {
    constexpr int AV = BM * BK / 4;
    for (int i = tid; i < AV; i += NT) {
      int r = i / (BK / 4);
      int c4 = (i % (BK / 4)) * 4;
      float4 v = make_float4(0.f, 0.f, 0.f, 0.f);
      int gr = bm + r;
      if (gr < M) v = *(const float4*)(A + (size_t)gr * K + k0 + c4);
      As[c4 + 0][r] = v.x; As[c4 + 1][r] = v.y; As[c4 + 2][r] = v.z; As[c4 + 3][r] = v.w;
    }
    constexpr int BV = BK * BN / 4;
    for (int i = tid; i < BV; i += NT) {
      int r = i / (BN / 4), c4 = (i % (BN / 4)) * 4;
      int gc = bn + c4, gk = k0 + r;
      float4 v = (gc < N1) ? *(const float4*)(B1 + (size_t)gk * s1 + gc)
                           : *(const float4*)(B2 + (size_t)gk * s2 + (gc - N1));
      Bs[r][c4 + 0] = v.x; Bs[r][c4 + 1] = v.y; Bs[r][c4 + 2] = v.z; Bs[r][c4 + 3] = v.w;
    }
    __syncthreads();
#pragma unroll
    for (int kk = 0; kk < BK; kk++) {
      float ra[TM], rb[TN];
#pragma unroll
      for (int i = 0; i < TM; i += 4)
        *(float4*)&ra[i] = *(const float4*)&As[kk][tm + i];
#pragma unroll
      for (int j = 0; j < TN; j += 4)
        *(float4*)&rb[j] = *(const float4*)&Bs[kk][tn + j];
#pragma unroll
      for (int i = 0; i < TM; i++)
#pragma unroll
        for (int j = 0; j < TN; j++) acc[i][j] += ra[i] * rb[j];
    }
    __syncthreads();
  }
#pragma unroll
  for (int i = 0; i < TM; i++) {
    int gr = bm + tm + i;
    if (gr >= M) continue;
#pragma unroll
    for (int j = 0; j < TN; j += 4) {
      float4 v;
      v.x = acc[i][j + 0]; v.y = acc[i][j + 1]; v.z = acc[i][j + 2]; v.w = acc[i][j + 3];
      if (bias) {
        v.x += bias[bn + tn + j + 0]; v.y += bias[bn + tn + j + 1];
        v.z += bias[bn + tn + j + 2]; v.w += bias[bn + tn + j + 3];
      }
      if (ACT == 1) {
        v.x = v.x > 0.f ? v.x : (__expf(v.x) - 1.f);
        v.y = v.y > 0.f ? v.y : (__expf(v.y) - 1.f);
        v.z = v.z > 0.f ? v.z : (__expf(v.z) - 1.f);
        v.w = v.w > 0.f ? v.w : (__expf(v.w) - 1.f);
      }
      *(float4*)(C + (size_t)gr * N + bn + tn + j) = v;
    }
  }
}

// ---------------- bf16 weight transpose ----------------
__global__ void k_cvtw(const float* __restrict__ l1w, const float* __restrict__ l2w,
                       short* __restrict__ w1t, short* __restrict__ w2t) {
  int t = blockIdx.x * 256 + threadIdx.x;
  if (t < 128 * 128) {
    int n = t >> 7, k = t & 127;
    w1t[t] = f2bf(l1w[k * 128 + n]);
  }
  if (t < 16 * 128) {
    int n = t >> 7, k = t & 127;
    w2t[t] = f2bf(l2w[k * 16 + n]);
  }
}

// ---------------- fused MLP: out1 = log_softmax(elu(noise1@W1+b1)@W2+b2) ----------------
// mlp1+mlp2 are block-local on the same 16-row-per-wave stripe, so t1 lives in a
// per-wave LDS tile (bf16 bits via f2bf -> bit-identical to the global round-trip).
// tls row stride 136 shorts = 272B (17x16): keeps every b128 read 16B-aligned.
__global__ __launch_bounds__(256) void k_mlpf(
    const short* __restrict__ A, const short* __restrict__ B1T,
    const float* __restrict__ b1, const short* __restrict__ B2T,
    const float* __restrict__ b2, float* __restrict__ out) {
  __shared__ __align__(16) short tls[4][16][136];
  int wv = threadIdx.x >> 6, lane = threadIdx.x & 63;
  int m0 = (blockIdx.x * 4 + wv) * 16;
  int quad = lane >> 4, ii = lane & 15;
  int mr = m0 + ii;
  bool mok = mr < NN;
  bf16x8 z = {0, 0, 0, 0, 0, 0, 0, 0};
  bf16x8 afr[4];
#pragma unroll
  for (int kt = 0; kt < 4; kt++)
    afr[kt] = mok ? *(const bf16x8*)(A + (size_t)mr * 128 + kt * 32 + quad * 8) : z;
  // layer 1: t1 = bf16(elu(A@W1 + b1)) into LDS
#pragma unroll
  for (int nt = 0; nt < 8; nt++) {
    f32x4 acc = {0.f, 0.f, 0.f, 0.f};
    int nc = nt * 16 + ii;
#pragma unroll
    for (int kt = 0; kt < 4; kt++) {
      bf16x8 bfr = *(const bf16x8*)(B1T + (size_t)nc * 128 + kt * 32 + quad * 8);
      acc = __builtin_amdgcn_mfma_f32_16x16x32_bf16(afr[kt], bfr, acc, 0, 0, 0);
    }
    float bval = b1[nc];
#pragma unroll
    for (int r = 0; r < 4; r++) {
      float v = acc[r] + bval;  // C/D: col=ii, row=quad*4+r
      v = v > 0.f ? v : (__expf(v) - 1.f);
      tls[wv][quad * 4 + r][nc] = f2bf(v);
    }
  }
  // layer 2: A-fragment row = ii, k-slice kt*32+quad*8 (same mapping as split mlp2)
  f32x4 acc2 = {0.f, 0.f, 0.f, 0.f};
#pragma unroll
  for (int kt = 0; kt < 4; kt++) {
    bf16x8 a2 = mok ? *(const bf16x8*)(&tls[wv][ii][kt * 32 + quad * 8]) : z;
    bf16x8 b2f = *(const bf16x8*)(B2T + (size_t)ii * 128 + kt * 32 + quad * 8);
    acc2 = __builtin_amdgcn_mfma_f32_16x16x32_bf16(a2, b2f, acc2, 0, 0, 0);
  }
  float bval2 = b2[ii];
#pragma unroll
  for (int r = 0; r < 4; r++) {
    float v = acc2[r] + bval2;
    float m = v;
#pragma unroll
    for (int o = 1; o <= 8; o <<= 1) m = fmaxf(m, __shfl_xor(m, o, 64));
    float e = __expf(v - m), s = e;
#pragma unroll
    for (int o = 1; o <= 8; o <<= 1) s += __shfl_xor(s, o, 64);
    int row = m0 + quad * 4 + r;
    if (row < NN) out[(size_t)row * NCLS + ii] = v - (m + logf(s));
  }
}

// order-preserving float->uint map (lex (score desc,id asc) == u64 desc compare)
__device__ __forceinline__ unsigned fkey(float f) {
  unsigned u = __float_as_uint(f);
  return u ^ (((int)u >> 31) | 0x80000000u);
}

// ===== k_fused1 helpers =====
#define SC1_MACRED()                                                         \
  _Pragma("unroll") for (int j_ = 0; j_ < 4; j_++) {                         \
    float a_, p_ = 0.f;                                                      \
    a_ = xv_[j_].x + xrv.x; p_ += fmaxf(a_, NEG * a_) * attv.x;              \
    a_ = xv_[j_].y + xrv.y; p_ += fmaxf(a_, NEG * a_) * attv.y;              \
    a_ = xv_[j_].z + xrv.z; p_ += fmaxf(a_, NEG * a_) * attv.z;              \
    a_ = xv_[j_].w + xrv.w; p_ += fmaxf(a_, NEG * a_) * attv.w;              \
    pp_[j_] = p_;                                                            \
  }                                                                          \
  _Pragma("unroll") for (int o_ = 1; o_ <= 4; o_ <<= 1)                      \
    _Pragma("unroll") for (int j_ = 0; j_ < 4; j_++)                         \
      pp_[j_] += __shfl_xor(pp_[j_], o_, 64);

#define SC1_FULL(Q, XC)                                                      \
  do {                                                                       \
    int s_[4]; float4 xv_[4]; float pp_[4];                                  \
    _Pragma("unroll") for (int j_ = 0; j_ < 4; j_++)                         \
      s_[j_] = __shfl(srcreg, (Q) + 2 * j_ + h2);                            \
    _Pragma("unroll") for (int j_ = 0; j_ < 4; j_++)                         \
      xv_[j_] = *(const float4*)(xlr + (size_t)s_[j_] * 256 + 4 * li);       \
    SC1_MACRED()                                                             \
    if ((li & 7) == 0) {                                                     \
      _Pragma("unroll") for (int j_ = 0; j_ < 4; j_++)                       \
        sc[w][(Q) + 2 * j_ + h2][headq] = pp_[j_];                           \
    }                                                                        \
    float4* xcp_ = (XC);                                                     \
    if (xcp_) {                                                              \
      _Pragma("unroll") for (int j_ = 0; j_ < 4; j_++) xcp_[j_] = xv_[j_];   \
    }                                                                        \
  } while (0)

#define SC1_TAIL(Q, XC)                                                      \
  do {                                                                       \
    int s_[4]; float4 xv_[4]; float pp_[4]; bool vv_[4];                     \
    _Pragma("unroll") for (int j_ = 0; j_ < 4; j_++) {                       \
      int r_ = (Q) + 2 * j_ + h2;                                            \
      s_[j_] = __shfl(srcreg, r_);                                           \
      vv_[j_] = r_ < deg;                                                    \
    }                                                                        \
    _Pragma("unroll") for (int j_ = 0; j_ < 4; j_++) {                       \
      xv_[j_] = make_float4(0.f, 0.f, 0.f, 0.f);                             \
      if (vv_[j_])                                                           \
        xv_[j_] = *(const float4*)(xlr + (size_t)s_[j_] * 256 + 4 * li);     \
    }                                                                        \
    SC1_MACRED()                                                             \
    if ((li & 7) == 0) {                                                     \
      _Pragma("unroll") for (int j_ = 0; j_ < 4; j_++)                       \
        if (vv_[j_]) sc[w][(Q) + 2 * j_ + h2][headq] = pp_[j_];              \
    }                                                                        \
    float4* xcp_ = (XC);                                                     \
    if (xcp_) {                                                              \
      _Pragma("unroll") for (int j_ = 0; j_ < 4; j_++) xcp_[j_] = xv_[j_];   \
    }                                                                        \
  } while (0)

#define AGG1_FMA(WV, XV)                                                     \
  do {                                                                       \
    float pw_ = fmaxf((WV), 0.f), nw_ = pw_ - (WV);                          \
    ao.x += pw_ * (XV).x; ao.y += pw_ * (XV).y;                              \
    ao.z += pw_ * (XV).z; ao.w += pw_ * (XV).w;                              \
    an.x += nw_ * (XV).x; an.y += nw_ * (XV).y;                              \
    an.z += nw_ * (XV).z; an.w += nw_ * (XV).w;                              \
  } while (0)

// ---------------- layer-1 fused: wave per dst, 4 dst per block ----------------
// (reverted to the round-2-bench artifact: 89.8us, VGPR 56, burst-8 scoring)
__global__ __launch_bounds__(256) void k_fused1(
    const float* __restrict__ xlr, const float* __restrict__ att,
    const int2* __restrict__ epair,
    const int* __restrict__ starts, const int* __restrict__ counts,
    const int* __restrict__ kptr, const float* __restrict__ bias,
    float* __restrict__ hout, short* __restrict__ nout) {
  __shared__ float sc[4][CAP][4];                 // [wave][edge][head]
  __shared__ __align__(16) ull keys[4][4][72];    // [wave][head][edge], 8-key padded
  int w = threadIdx.x >> 6;
  int l = threadIdx.x & 63;
  int d = blockIdx.x * 4 + w;
  if (d >= NN) return;  // wave-uniform
  int st = starts[d];
  int deg = counts[d];
  if (deg > CAP) deg = CAP;
  int k = kptr[0];

  int srcreg = 0, idreg = 0x7fffffff;
  if (l < deg) { int2 pe = epair[st + l]; srcreg = pe.x; idreg = pe.y; }

  int h2 = l >> 5, li = l & 31;
  int headq = li >> 3;
  float4 xrv = *(const float4*)(xlr + (size_t)d * 256 + 128 + 4 * li);
  float4 attv = *(const float4*)(att + 4 * li);
  float4 b1v = *(const float4*)(bias + 4 * li);

  // ---- scoring ----
  float4 xc[8];
  if (deg >= 16) {
    int s_[8];
#pragma unroll
    for (int j = 0; j < 8; j++) s_[j] = __shfl(srcreg, 2 * j + h2);
#pragma unroll
    for (int j = 0; j < 8; j++)
      xc[j] = *(const float4*)(xlr + (size_t)s_[j] * 256 + 4 * li);
    float pp_[8];
#pragma unroll
    for (int j = 0; j < 8; j++) {
      float a_, p_ = 0.f;
      a_ = xc[j].x + xrv.x; p_ += fmaxf(a_, NEG * a_) * attv.x;
      a_ = xc[j].y + xrv.y; p_ += fmaxf(a_, NEG * a_) * attv.y;
      a_ = xc[j].z + xrv.z; p_ += fmaxf(a_, NEG * a_) * attv.z;
      a_ = xc[j].w + xrv.w; p_ += fmaxf(a_, NEG * a_) * attv.w;
      pp_[j] = p_;
    }
#pragma unroll
    for (int o_ = 1; o_ <= 4; o_ <<= 1)
#pragma unroll
      for (int j = 0; j < 8; j++) pp_[j] += __shfl_xor(pp_[j], o_, 64);
    if ((li & 7) == 0) {
#pragma unroll
      for (int j = 0; j < 8; j++) sc[w][2 * j + h2][headq] = pp_[j];
    }
  } else {
    if (deg >= 8) SC1_FULL(0, xc);
    else if (deg > 0) SC1_TAIL(0, xc);
    if (deg > 8) SC1_TAIL(8, xc + 4);
  }
  for (int q = 16; q < deg; q += 8) {
    if (q + 8 <= deg) SC1_FULL(q, (float4*)0);
    else SC1_TAIL(q, (float4*)0);
  }

  // ---- top-k via u64-key rank counting (zero-padded, b128-chunked) ----
  int hh = l >> 4, ii = l & 15;
  float sv[4]; bool val[4]; ull mkey[4];
#pragma unroll
  for (int j = 0; j < 4; j++) {
    int q = j * 16 + ii;
    val[j] = q < deg;
    sv[j] = val[j] ? sc[w][q][hh] : NINF;
    int bid = __shfl(idreg, q);
    mkey[j] = val[j] ? (((ull)fkey(sv[j]) << 32) | (unsigned)~bid) : 0ull;
    if (val[j]) keys[w][hh][q] = mkey[j];
  }
  if (ii < 8) keys[w][hh][deg + ii] = 0ull;  // pad: zero key never outranks
  const ull* kp = keys[w][hh];
  int nch = (deg + 7) >> 3;
  int rk0 = 0, rk1 = 0, rk2 = 0, rk3 = 0;
  if (deg <= 16) {
    for (int c = 0; c < nch; c++) {
      const ull2* p2 = (const ull2*)(kp + c * 8);
      ull2 A_ = p2[0], B_ = p2[1];
      rk0 += (int)(A_[0] > mkey[0]) + (int)(A_[1] > mkey[0]) +
             (int)(B_[0] > mkey[0]) + (int)(B_[1] > mkey[0]);
      ull2 C_ = p2[2], D_ = p2[3];
      rk0 += (int)(C_[0] > mkey[0]) + (int)(C_[1] > mkey[0]) +
             (int)(D_[0] > mkey[0]) + (int)(D_[1] > mkey[0]);
    }
  } else if (deg <= 32) {
    for (int c = 0; c < nch; c++) {
      const ull2* p2 = (const ull2*)(kp + c * 8);
      ull2 A_ = p2[0], B_ = p2[1];
      rk0 += (int)(A_[0] > mkey[0]) + (int)(A_[1] > mkey[0]) +
             (int)(B_[0] > mkey[0]) + (int)(B_[1] > mkey[0]);
      rk1 += (int)(A_[0] > mkey[1]) + (int)(A_[1] > mkey[1]) +
             (int)(B_[0] > mkey[1]) + (int)(B_[1] > mkey[1]);
      ull2 C_ = p2[2], D_ = p2[3];
      rk0 += (int)(C_[0] > mkey[0]) + (int)(C_[1] > mkey[0]) +
             (int)(D_[0] > mkey[0]) + (int)(D_[1] > mkey[0]);
      rk1 += (int)(C_[0] > mkey[1]) + (int)(C_[1] > mkey[1]) +
             (int)(D_[0] > mkey[1]) + (int)(D_[1] > mkey[1]);
    }
  } else {
    for (int c = 0; c < nch; c++) {
      const ull2* p2 = (const ull2*)(kp + c * 8);
      ull2 A_ = p2[0], B_ = p2[1];
      rk0 += (int)(A_[0] > mkey[0]) + (int)(A_[1] > mkey[0]) +
             (int)(B_[0] > mkey[0]) + (int)(B_[1] > mkey[0]);
      rk1 += (int)(A_[0] > mkey[1]) + (int)(A_[1] > mkey[1]) +
             (int)(B_[0] > mkey[1]) + (int)(B_[1] > mkey[1]);
      rk2 += (int)(A_[0] > mkey[2]) + (int)(A_[1] > mkey[2]) +
             (int)(B_[0] > mkey[2]) + (int)(B_[1] > mkey[2]);
      rk3 += (int)(A_[0] > mkey[3]) + (int)(A_[1] > mkey[3]) +
             (int)(B_[0] > mkey[3]) + (int)(B_[1] > mkey[3]);
      ull2 C_ = p2[2], D_ = p2[3];
      rk0 += (int)(C_[0] > mkey[0]) + (int)(C_[1] > mkey[0]) +
             (int)(D_[0] > mkey[0]) + (int)(D_[1] > mkey[0]);
      rk1 += (int)(C_[0] > mkey[1]) + (int)(C_[1] > mkey[1]) +
             (int)(D_[0] > mkey[1]) + (int)(D_[1] > mkey[1]);
      rk2 += (int)(C_[0] > mkey[2]) + (int)(C_[1] > mkey[2]) +
             (int)(D_[0] > mkey[2]) + (int)(D_[1] > mkey[2]);
      rk3 += (int)(C_[0] > mkey[3]) + (int)(C_[1] > mkey[3]) +
             (int)(D_[0] > mkey[3]) + (int)(D_[1] > mkey[3]);
    }
  }
  bool kept[4];
  kept[0] = val[0] && (rk0 < k);
  kept[1] = val[1] && (rk1 < k);
  kept[2] = val[2] && (rk2 < k);
  kept[3] = val[3] && (rk3 < k);

  // ---- dual softmax, no max-shift (scores bounded; exp can't overflow fp32) ----
  float ek[4], en[4], sk = 0.f, sn = 0.f;
#pragma unroll
  for (int j = 0; j < 4; j++) {
    float e_ = __expf(sv[j]);  // exp(NINF) = 0 for invalid lanes
    ek[j] = kept[j] ? e_ : 0.f;
    en[j] = (val[j] && !kept[j]) ? e_ : 0.f;
    sk += ek[j]; sn += en[j];
  }
#pragma unroll
  for (int o = 1; o <= 8; o <<= 1) {
    sk += __shfl_xor(sk, o, 64);
    sn += __shfl_xor(sn, o, 64);
  }
  float ik = 1.f / (sk + 1e-16f), inn = 1.f / (sn + 1e-16f);
#pragma unroll
  for (int j = 0; j < 4; j++) {
    if (val[j]) sc[w][j * 16 + ii][hh] = kept[j] ? ek[j] * ik : -(en[j] * inn);
  }

  // ---- aggregation: rows <16 from registers, tail from global ----
  float4 ao = make_float4(0.f, 0.f, 0.f, 0.f), an = ao;
  if (deg >= 16) {
#pragma unroll
    for (int j = 0; j < 8; j++) {
      float wv = sc[w][2 * j + h2][headq];
      AGG1_FMA(wv, xc[j]);
    }
  } else {
#pragma unroll
    for (int j = 0; j < 8; j++) {
      int r = 2 * j + h2;
      if (r < deg) {
        float wv = sc[w][r][headq];
        AGG1_FMA(wv, xc[j]);
      }
    }
  }
  for (int q = 16; q < deg; q += 8) {
    int s_[4];
#pragma unroll
    for (int j = 0; j < 4; j++) s_[j] = __shfl(srcreg, q + 2 * j + h2);
    if (q + 8 <= deg) {
#pragma unroll
      for (int j = 0; j < 4; j++) {
        float wv = sc[w][q + 2 * j + h2][headq];
        float4 xv = *(const float4*)(xlr + (size_t)s_[j] * 256 + 4 * li);
        AGG1_FMA(wv, xv);
      }
    } else {
#pragma unroll
      for (int j = 0; j < 4; j++) {
        int r = q + 2 * j + h2;
        if (r < deg) {
          float wv = sc[w][r][headq];
          float4 xv = *(const float4*)(xlr + (size_t)s_[j] * 256 + 4 * li);
          AGG1_FMA(wv, xv);
        }
      }
    }
  }
  ao.x += __shfl_xor(ao.x, 32, 64); ao.y += __shfl_xor(ao.y, 32, 64);
  ao.z += __shfl_xor(ao.z, 32, 64); ao.w += __shfl_xor(ao.w, 32, 64);
  an.x += __shfl_xor(an.x, 32, 64); an.y += __shfl_xor(an.y, 32, 64);
  an.z += __shfl_xor(an.z, 32, 64); an.w += __shfl_xor(an.w, 32, 64);
  if (h2 == 0) {
    float4 vo;
    vo.x = ao.x + b1v.x; vo.y = ao.y + b1v.y; vo.z = ao.z + b1v.z; vo.w = ao.w + b1v.w;
    vo.x = vo.x > 0.f ? vo.x : (__expf(vo.x) - 1.f);
    vo.y = vo.y > 0.f ? vo.y : (__expf(vo.y) - 1.f);
    vo.z = vo.z > 0.f ? vo.z : (__expf(vo.z) - 1.f);
    vo.w = vo.w > 0.f ? vo.w : (__expf(vo.w) - 1.f);
    *(float4*)(hout + (size_t)d * D1 + 4 * li) = vo;
  } else {
    short4 vn;
    vn.x = f2bf(an.x + b1v.x); vn.y = f2bf(an.y + b1v.y);
    vn.z = f2bf(an.z + b1v.z); vn.w = f2bf(an.w + b1v.w);
    *(short4*)(nout + (size_t)d * D1 + 4 * li) = vn;
  }
}

// ===== k_fused2 helpers =====
#define SC2_RED(P0, P1)                                                      \
  _Pragma("unroll") for (int o_ = 1; o_ <= 8; o_ <<= 1) {                    \
    P0 += __shfl_xor(P0, o_, 64);                                            \
    P1 += __shfl_xor(P1, o_, 64);                                            \
  }

#define SC2_FULL(Q, CB)                                                      \
  do {                                                                       \
    int s0_ = __shfl(srcreg, (Q) + g);                                       \
    int s1_ = __shfl(srcreg, (Q) + 4 + g);                                   \
    float x0_ = xlr[(size_t)s0_ * 32 + li];                                  \
    float x1_ = xlr[(size_t)s1_ * 32 + li];                                  \
    constexpr int cb_ = (CB) < 0 ? 0 : (CB);                                 \
    if ((CB) >= 0) { xc[cb_] = x0_; xc[cb_ + 1] = x1_; }                     \
    float a0_ = x0_ + xrv, a1_ = x1_ + xrv;                                  \
    float p0_ = fmaxf(a0_, NEG * a0_) * attv;                                \
    float p1_ = fmaxf(a1_, NEG * a1_) * attv;                                \
    SC2_RED(p0_, p1_)                                                        \
    if (li == 0) { sc[w][(Q) + g] = p0_; sc[w][(Q) + 4 + g] = p1_; }         \
  } while (0)

#define SC2_TAIL(Q, CB)                                                      \
  do {                                                                       \
    int r0_ = (Q) + g, r1_ = (Q) + 4 + g;                                    \
    int s0_ = __shfl(srcreg, r0_);                                           \
    int s1_ = __shfl(srcreg, r1_);                                           \
    float x0_ = (r0_ < deg) ? xlr[(size_t)s0_ * 32 + li] : 0.f;              \
    float x1_ = (r1_ < deg) ? xlr[(size_t)s1_ * 32 + li] : 0.f;              \
    constexpr int cb_ = (CB) < 0 ? 0 : (CB);                                 \
    if ((CB) >= 0) { xc[cb_] = x0_; xc[cb_ + 1] = x1_; }                     \
    float a0_ = x0_ + xrv, a1_ = x1_ + xrv;                                  \
    float p0_ = fmaxf(a0_, NEG * a0_) * attv;                                \
    float p1_ = fmaxf(a1_, NEG * a1_) * attv;                                \
    SC2_RED(p0_, p1_)                                                        \
    if (li == 0) {                                                           \
      if (r0_ < deg) sc[w][r0_] = p0_;                                       \
      if (r1_ < deg) sc[w][r1_] = p1_;                                       \
    }                                                                        \
  } while (0)

// ---------------- layer-2 fused (xlr2 [NN][32]: cols 0-15 xl, 16-31 xr) ----------------
__global__ __launch_bounds__(256) void k_fused2(
    const float* __restrict__ xlr, const float* __restrict__ att,
    const int2* __restrict__ epair,
    const int* __restrict__ starts, const int* __restrict__ counts,
    const int* __restrict__ kptr, const float* __restrict__ bias,
    float* __restrict__ out0, float* __restrict__ out1) {
  __shared__ float sc[4][CAP];
  __shared__ __align__(16) ull keys[4][72];
  int w = threadIdx.x >> 6;
  int l = threadIdx.x & 63;
  int d = blockIdx.x * 4 + w;
  if (d >= NN) return;
  int st = starts[d];
  int deg = counts[d];
  if (deg > CAP) deg = CAP;
  int k = kptr[0];

  int srcreg = 0, idreg = 0x7fffffff;
  if (l < deg) { int2 pe = epair[st + l]; srcreg = pe.x; idreg = pe.y; }

  int g = l >> 4, li = l & 15;
  float xrv = xlr[(size_t)d * 32 + 16 + li];
  float attv = att[li];
  float bv2 = bias[li];

  // ---- scoring: full groups unchecked; rows <32 register-cached ----
  float xc[8];
  if (deg >= 8) SC2_FULL(0, 0); else SC2_TAIL(0, 0);
  if (deg > 8)  { if (deg >= 16) SC2_FULL(8, 2);  else SC2_TAIL(8, 2); }
  if (deg > 16) { if (deg >= 24) SC2_FULL(16, 4); else SC2_TAIL(16, 4); }
  if (deg > 24) { if (deg >= 32) SC2_FULL(24, 6); else SC2_TAIL(24, 6); }
  for (int q = 32; q < deg; q += 8) {
    if (q + 8 <= deg) SC2_FULL(q, -1);
    else SC2_TAIL(q, -1);
  }

  // ---- top-k via u64 keys: lane = edge; zero-padded, b128-chunked rank ----
  float sv = (l < deg) ? sc[w][l] : NINF;
  ull mk64 = (l < deg) ? (((ull)fkey(sv) << 32) | (unsigned)~idreg) : 0ull;
  if (l < deg) keys[w][l] = mk64;
  if (l < 8) keys[w][deg + l] = 0ull;
  int rank = 0;
  int nch = (deg + 7) >> 3;
  for (int c = 0; c < nch; c++) {
    const ull2* p2 = (const ull2*)(keys[w] + c * 8);
    ull2 A_ = p2[0], B_ = p2[1];
    rank += (int)(A_[0] > mk64) + (int)(A_[1] > mk64) +
            (int)(B_[0] > mk64) + (int)(B_[1] > mk64);
    ull2 C_ = p2[2], D_ = p2[3];
    rank += (int)(C_[0] > mk64) + (int)(C_[1] > mk64) +
            (int)(D_[0] > mk64) + (int)(D_[1] > mk64);
  }
  bool kept = (l < deg) && (rank < k);

  // ---- dual softmax, no max-shift ----
  float e_ = __expf(sv);
  float ek = kept ? e_ : 0.f;
  float en = ((l < deg) && !kept) ? e_ : 0.f;
  float sk = ek, sn = en;
#pragma unroll
  for (int o = 1; o <= 32; o <<= 1) {
    sk += __shfl_xor(sk, o, 64);
    sn += __shfl_xor(sn, o, 64);
  }
  if (l < deg) sc[w][l] = kept ? ek / (sk + 1e-16f) : -(en / (sn + 1e-16f));

  // ---- aggregation: rows <32 from registers, tail from global ----
  float ao = 0.f, an = 0.f;
  if (deg >= 32) {
#pragma unroll
    for (int j = 0; j < 8; j++) {
      float wv = sc[w][4 * j + g];
      float pw = fmaxf(wv, 0.f), nw = pw - wv;
      ao += pw * xc[j]; an += nw * xc[j];
    }
  } else {
#pragma unroll
    for (int j = 0; j < 8; j++) {
      int r = 4 * j + g;
      if (r < deg) {
        float wv = sc[w][r];
        float pw = fmaxf(wv, 0.f), nw = pw - wv;
        ao += pw * xc[j]; an += nw * xc[j];
      }
    }
  }
  for (int q = 32; q < deg; q += 8) {
    int s0 = __shfl(srcreg, q + g), s1 = __shfl(srcreg, q + 4 + g);
    if (q + 8 <= deg) {
      { float wv = sc[w][q + g];
        float pw = fmaxf(wv, 0.f), nw = pw - wv;
        float xv = xlr[(size_t)s0 * 32 + li];
        ao += pw * xv; an += nw * xv; }
      { float wv = sc[w][q + 4 + g];
        float pw = fmaxf(wv, 0.f), nw = pw - wv;
        float xv = xlr[(size_t)s1 * 32 + li];
        ao += pw * xv; an += nw * xv; }
    } else {
      int r0 = q + g, r1 = q + 4 + g;
      if (r0 < deg) {
        float wv = sc[w][r0];
        float pw = fmaxf(wv, 0.f), nw = pw - wv;
        float xv = xlr[(size_t)s0 * 32 + li];
        ao += pw * xv; an += nw * xv;
      }
      if (r1 < deg) {
        float wv = sc[w][r1];
        float pw = fmaxf(wv, 0.f), nw = pw - wv;
        float xv = xlr[(size_t)s1 * 32 + li];
        ao += pw * xv; an += nw * xv;
      }
    }
  }
  ao += __shfl_xor(ao, 16, 64); ao += __shfl_xor(ao, 32, 64);
  an += __shfl_xor(an, 16, 64); an += __shfl_xor(an, 32, 64);
  float vo = ao + bv2, vn = an + bv2;
  float mo = vo, mv = vn;
#pragma unroll
  for (int o = 1; o <= 8; o <<= 1) {
    mo = fmaxf(mo, __shfl_xor(mo, o, 64));
    mv = fmaxf(mv, __shfl_xor(mv, o, 64));
  }
  float eo = __expf(vo - mo), ev = __expf(vn - mv);
#pragma unroll
  for (int o = 1; o <= 8; o <<= 1) {
    eo += __shfl_xor(eo, o, 64);
    ev += __shfl_xor(ev, o, 64);
  }
  if (g == 0) out0[(size_t)d * NCLS + li] = vo - (mo + logf(eo));
  if (g == 1) out1[(size_t)d * NCLS + li] = vn - (mv + logf(ev));
}

extern "C" void kernel_launch(void* const* d_in, const int* in_sizes, int n_in,
                              void* d_out, int out_size, void* d_ws, size_t ws_size,
                              hipStream_t stream) {
  (void)in_sizes; (void)n_in; (void)out_size; (void)ws_size;
  const float* x    = (const float*)d_in[0];
  const int*   ei   = (const int*)d_in[1];
  const int*   kptr = (const int*)d_in[2];
  const float* Wl1  = (const float*)d_in[3];
  const float* Wr1  = (const float*)d_in[4];
  const float* att1 = (const float*)d_in[5];
  const float* b1   = (const float*)d_in[6];
  const float* Wl2  = (const float*)d_in[7];
  const float* Wr2  = (const float*)d_in[8];
  const float* att2 = (const float*)d_in[9];
  const float* b2   = (const float*)d_in[10];
  const float* l1w  = (const float*)d_in[11];
  const float* l1b  = (const float*)d_in[12];
  const float* l2w  = (const float*)d_in[13];
  const float* l2b  = (const float*)d_in[14];
  const int* srcv = ei;
  const int* dstv = ei + NE;

  char* wp = (char*)d_ws;
  auto alloc = [&](size_t n) { char* p = wp; wp += (n + 255) & ~(size_t)255; return p; };
  float* xlr1   = (float*)alloc((size_t)NN * 256 * 4);  // [NN][256] xl|xr
  float* hbuf   = (float*)alloc((size_t)NN * D1 * 4);   // h = elu(out1+b1)
  short* noise1 = (short*)alloc((size_t)NN * D1 * 2);   // bf16
  float* xlr2   = (float*)alloc((size_t)NN * 32 * 4);   // [NN][32] xl2|xr2
  short* w1t    = (short*)alloc((size_t)128 * 128 * 2); // l1w^T bf16
  short* w2t    = (short*)alloc((size_t)16 * 128 * 2);  // l2w^T bf16
  int* counts = (int*)alloc((size_t)NN * 4);
  int* starts = (int*)alloc((size_t)NN * 4);
  int* cursor = (int*)alloc((size_t)NN * 4);
  int2* epair = (int2*)alloc((size_t)NE * 8);           // packed (src, edge id)
  int* bsum   = (int*)alloc((size_t)NSB * 4);
  int* boff   = (int*)alloc((size_t)NSB * 4);

  // CSR build (by dst) — parallel 3-phase scan
  hipMemsetAsync(counts, 0, (size_t)NN * 4, stream);
  k_count<<<(NE + 255) / 256, 256, 0, stream>>>(dstv, counts);
  k_scanA<<<NSB, 256, 0, stream>>>(counts, bsum);
  k_scanB<<<1, 256, 0, stream>>>(bsum, boff);
  k_scanC<<<NSB, 256, 0, stream>>>(counts, boff, starts, cursor);
  k_scatter<<<(NE + 255) / 256, 256, 0, stream>>>(srcv, dstv, cursor, epair);

  // bf16 weight transpose for the MLP
  k_cvtw<<<64, 256, 0, stream>>>(l1w, l2w, w1t, w2t);

  // Layer 1 node transforms: x @ [Wl1|Wr1] -> xlr1 [NN][256]  (baseline tiling)
  k_gemm2<64, 128, 32, 4, 8, 0><<<dim3(2, (NN + 63) / 64), 256, 0, stream>>>(
      x, Wl1, Wr1, 128, 128, 128, nullptr, xlr1, NN, 256, FIN);

  // Layer 1 fused edge pipeline (noise1 written as bf16)
  k_fused1<<<(NN + 3) / 4, 256, 0, stream>>>(xlr1, att1, epair,
                                             starts, counts, kptr, b1, hbuf, noise1);

  float* o = (float*)d_out;

  // Fused MLP on noise1: output1 = log_softmax(elu(noise1@l1w+l1b)@l2w+l2b)
  k_mlpf<<<(NN + 63) / 64, 256, 0, stream>>>(noise1, w1t, l1b, w2t, l2b,
                                             o + (size_t)NN * NCLS);

  // Layer 2 node transforms: h @ [Wl2|Wr2] -> xlr2 [NN][32]
  k_gemm2<128, 32, 32, 4, 4, 0><<<dim3(1, (NN + 127) / 128), 256, 0, stream>>>(
      hbuf, Wl2, Wr2, 16, 16, 16, nullptr, xlr2, NN, 32, D1);

  // Layer 2 fused edge pipeline (+log_softmax epilogue) -> final outputs
  k_fused2<<<(NN + 3) / 4, 256, 0, stream>>>(xlr2, att2, epair, starts,
                                             counts, kptr, b2, o,
                                             o + (size_t)2 * NN * NCLS);
}